// Round 5
// baseline (273.216 us; speedup 1.0000x reference)
//
#include <hip/hip_runtime.h>
#include <hip/hip_bf16.h>

#define BATCH 1024
#define NV 5023
#define NJOINT 5
#define NLMK 51
#define N3 (NV*3)        // 15069
#define NPADB 15072      // N3 padded to multiple of 48 (and of 16)
#define KBETA 400
#define KTOT 448         // 400 betas + 36 pose_feature + 12 zero pad
#define NSTEP 14         // KTOT/32 MFMA k-steps
#define RB_B (NPADB/16)  // 942 row-blocks in Wb
#define FRAG 512         // elems per (R,s) fragment: 64 lanes * 8 bf16

#define BM 64            // batches per block (small path)
#define BN 48            // output cols per block = 16 vertices (small path)
#define NVC 128          // v-chunks for js_part
#define CVT_BLKS 3297    // RB_B*14*64/256 = 844032/256 chunks of 16B

// big-path GEMM geometry: tile-split, no inter-wave reduction
#define GBM 64           // batches per block
#define GBN 192          // output cols per block = 64 vertices
#define GNP 79           // ceil(5023/64) panels
#define GGRID 1280       // ceil(79/8)*8 * 16 m-blocks
#define CH_S 52          // chunk stride (floats): 4*52 % 32 == 16 -> 2-way = free

typedef __attribute__((ext_vector_type(8))) short short8;
typedef __attribute__((ext_vector_type(4))) float floatx4;
typedef __attribute__((ext_vector_type(4))) float float4v;

// ---------------- workspace byte offsets ----------------
#define WS_JS      0          // 6000 f32
#define WS_BASEJ   24064      // 15 f32
#define WS_REG     24512      // 1 f32
#define WS_FLAGS   24520      // 2 ints (fallback path only)
#define WS_AMAT    24576      // 1024*60 f32   -> ends 270336
#define WS_ACT     270336     // 1024*448 bf16 (fragment-linear) -> ends 1187840
#define WS_WB      1187840    // 15072*448 bf16 (fragment-linear) -> ends 14692352
#define WS_FULL    14692352

__device__ __forceinline__ float ldf(const void* p, long i, int f32) {
    if (f32) return ((const float*)p)[i];
    return __bfloat162float(((const __hip_bfloat16*)p)[i]);
}
__device__ __forceinline__ short8 ld8bf(const void* p, long i, int f32) {
    if (f32) {
        // vectorized: two float4 loads (callers guarantee 16B alignment)
        float4v a = *(const float4v*)((const float*)p + i);
        float4v b = *(const float4v*)((const float*)p + i + 4);
        short8 r;
#pragma unroll
        for (int j = 0; j < 4; ++j) {
            __hip_bfloat16 h = __float2bfloat16(a[j]);
            r[j] = *reinterpret_cast<short*>(&h);
        }
#pragma unroll
        for (int j = 0; j < 4; ++j) {
            __hip_bfloat16 h = __float2bfloat16(b[j]);
            r[4 + j] = *reinterpret_cast<short*>(&h);
        }
        return r;
    }
    return *(const short8*)((const __hip_bfloat16*)p + i);
}
__device__ __forceinline__ void stf(void* p, long i, float v, int f32) {
    if (f32) ((float*)p)[i] = v;
    else ((__hip_bfloat16*)p)[i] = __float2bfloat16(v);
}

// fragment-linear Act index: element (batch-row b, k) -> bf16 elem offset.
// fragment (Ra = b>>4, s = k>>5) is 512 contiguous elems; lane = quad*16+fr
// holds row fr = b&15, k-chunk quad = (k>>3)&3, elem e = k&7.
__device__ __forceinline__ long act2_off(int b, int k) {
    return (((long)(b >> 4) * NSTEP + (k >> 5)) * 64 + ((k >> 3) & 3) * 16 + (b & 15)) * 8 + (k & 7);
}

// per-wave inline dtype probe: f32 data read as bf16 halfwords blows past 1e4
__device__ __forceinline__ int probe_f32(const void* shape_p) {
    int lane = threadIdx.x & 63;
    unsigned short h = ((const unsigned short*)shape_p)[2 * lane];
    union { unsigned short u; __hip_bfloat16 b; } cv; cv.u = h;
    float v = fabsf(__bfloat162float(cv.b));
    if (v != v) v = 3.4e38f;
#pragma unroll
    for (int off = 32; off; off >>= 1) v = fmaxf(v, __shfl_down(v, off));
    v = __shfl(v, 0);
    return v > 1e4f;
}
__device__ __forceinline__ int probe_i64(const void* lmk_idx) {
    int lane = threadIdx.x & 63;
    const int* q = (const int*)lmk_idx;
    int odd_nonzero = (lane < 25) && (q[2*lane + 1] != 0);
    unsigned long long b = __ballot(odd_nonzero);
    return b == 0ull;
}

// fallback-path init: zero JS/baseJ/reg + write flags
__global__ void k_init(float* ws0, const void* shape_p, const void* lmk_idx, int* flags) {
    int i = blockIdx.x * 256 + threadIdx.x;
    if (i < 6129) ws0[i] = 0.f;
    if (blockIdx.x == 0 && threadIdx.x < 64) {
        int f = probe_f32(shape_p);
        int i64 = probe_i64(lmk_idx);
        if (threadIdx.x == 0) { flags[0] = f; flags[1] = i64; }
    }
}

// Fused prep (big path): blocks [0,CVT_BLKS) pack Wb in FRAGMENT-LINEAR
// layout (thread g writes contiguous 16B chunk #g); blocks [CVT_BLKS, +384)
// compute js partial sums from RAW shapedirs (independent -> concurrent).
__global__ __launch_bounds__(256) void k_prep(const void* __restrict__ shapedirs,
                                              const void* __restrict__ posedirs,
                                              const void* __restrict__ Jreg,
                                              const void* __restrict__ v_template,
                                              const void* __restrict__ shape_p,
                                              float* __restrict__ reg,
                                              __hip_bfloat16* __restrict__ Wb,
                                              float* __restrict__ PART) {
    int f32 = probe_f32(shape_p);
    int blk = blockIdx.x, tid = threadIdx.x;
    if (blk < CVT_BLKS) {
        if (blk == 0 && tid == 0) reg[0] = 0.f;
        int g = blk * 256 + tid;          // chunk index < 844032
        int R = g / (NSTEP * 64);
        int rem = g - R * (NSTEP * 64);
        int s = rem >> 6;
        int l = rem & 63;
        int quad = l >> 4, fr = l & 15;
        int n = R * 16 + fr;              // Wb row
        int k0 = s * 32 + quad * 8;       // first k of this 8-elem chunk
        short8 o;
#pragma unroll
        for (int e = 0; e < 8; ++e) o[e] = 0;
        if (n < N3) {
            if (k0 < KBETA) {
                o = ld8bf(shapedirs, (long)n * KBETA + k0, f32);
            } else if (k0 < 440) {
#pragma unroll
                for (int e = 0; e < 8; ++e) {
                    int kk = k0 + e - KBETA;
                    float val = (kk < 36) ? ldf(posedirs, (long)kk * N3 + n, f32) : 0.f;
                    __hip_bfloat16 h = __float2bfloat16(val);
                    o[e] = *reinterpret_cast<short*>(&h);
                }
            }
        }
        *(short8*)(Wb + (long)g * 8) = o;
    } else {
        int b2 = blk - CVT_BLKS;     // 0..383
        int k = b2 >> 7;             // 0..2
        int vc = b2 & 127;           // 0..127
        int v0 = vc * 40, v1 = min(NV, v0 + 40);
        int l2 = tid + 256;          // 400 == template col
        float acc1[NJOINT] = {0,0,0,0,0};
        float acc2[NJOINT] = {0,0,0,0,0};
        for (int v = v0; v < v1; ++v) {
            float s1 = ldf(shapedirs, (long)v*1200 + k*400 + tid, f32);
            float s2 = 0.f;
            if (l2 < 400)       s2 = ldf(shapedirs, (long)v*1200 + k*400 + l2, f32);
            else if (l2 == 400) s2 = ldf(v_template, v*3 + k, f32);
#pragma unroll
            for (int j = 0; j < NJOINT; ++j) {
                float jr = ldf(Jreg, j*NV + v, f32);
                acc1[j] += jr * s1;
                acc2[j] += jr * s2;
            }
        }
        long base = ((long)(k*NVC + vc)*5)*401;
#pragma unroll
        for (int j = 0; j < NJOINT; ++j) {
            PART[base + j*401 + tid] = acc1[j];
            if (l2 <= 400) PART[base + j*401 + l2] = acc2[j];
        }
    }
}

// Reduce over NVC chunks -> JS / baseJ.
__global__ __launch_bounds__(256) void k_js_red(const float* __restrict__ PART,
                                                float* __restrict__ JS,
                                                float* __restrict__ baseJ) {
    int o = blockIdx.x * 256 + threadIdx.x;
    if (o >= 3*5*401) return;
    int k = o / 2005, r = o - k*2005;
    int j = r / 401, l = r - j*401;
    float s = 0.f;
    long base = ((long)(k*NVC)*5 + j)*401 + l;
    for (int vc = 0; vc < NVC; ++vc) s += PART[base + (long)vc*2005];
    if (l < 400) JS[j*1200 + k*400 + l] = s;
    else         baseJ[j*3 + k] = s;
}

// Fallback JS (atomic, raw shapedirs) for small ws.
__global__ void k_js_atomic(const void* __restrict__ Jreg,
                            const void* __restrict__ shapedirs,
                            const void* __restrict__ v_template,
                            const int* __restrict__ flags,
                            float* __restrict__ JS, float* __restrict__ baseJ) {
    int f32 = flags[0];
    int k = blockIdx.x, vc = blockIdx.y, tid = threadIdx.x;
    int v0 = vc * 79, v1 = min(NV, v0 + 79);
    int l2 = tid + 256;
    float acc1[NJOINT] = {0,0,0,0,0};
    float acc2[NJOINT] = {0,0,0,0,0};
    for (int v = v0; v < v1; ++v) {
        float s1 = ldf(shapedirs, (long)v*1200 + k*400 + tid, f32);
        float s2 = 0.f;
        if (l2 < 400)       s2 = ldf(shapedirs, (long)v*1200 + k*400 + l2, f32);
        else if (l2 == 400) s2 = ldf(v_template, v*3 + k, f32);
#pragma unroll
        for (int j = 0; j < NJOINT; ++j) {
            float jr = ldf(Jreg, j*NV + v, f32);
            acc1[j] += jr * s1;
            acc2[j] += jr * s2;
        }
    }
#pragma unroll
    for (int j = 0; j < NJOINT; ++j) {
        atomicAdd(&JS[j*1200 + k*400 + tid], acc1[j]);
        if (l2 < 400)       atomicAdd(&JS[j*1200 + k*400 + l2], acc2[j]);
        else if (l2 == 400) atomicAdd(&baseJ[j*3 + k], acc2[j]);
    }
}

// Per-batch: betas->Act(bf16, fragment-linear), joints, rodrigues, chain, A, reg
__global__ __launch_bounds__(64) void k_batch(
        const void* __restrict__ shape_p, const void* __restrict__ expr_p,
        const void* __restrict__ grot, const void* __restrict__ neck,
        const void* __restrict__ jaw,  const void* __restrict__ eye,
        const float* __restrict__ JS, const float* __restrict__ baseJ,
        __hip_bfloat16* __restrict__ Act, float* __restrict__ Amat, float* __restrict__ reg) {
    int f32 = probe_f32(shape_p);
    int b = blockIdx.x, tid = threadIdx.x;
    __shared__ float betas[400];
    __shared__ float Rm[NJOINT][9];
    __shared__ float joints[NJOINT][3];
    __shared__ float Gm[NJOINT][12];

    for (int i = tid; i < 400; i += 64) {
        float v = (i < 300) ? ldf(shape_p, b*300 + i, f32)
                            : ldf(expr_p, b*100 + i - 300, f32);
        betas[i] = v;
        Act[act2_off(b, i)] = __float2bfloat16(v);
    }
    if (tid >= 36 && tid < 48) Act[act2_off(b, 400 + tid)] = __float2bfloat16(0.f);
    __syncthreads();

    if (tid < 60) {
        int o = tid % 15, q = tid / 15;
        int j = o / 3, kk = o - 3*j;
        const float* js = &JS[j*1200 + kk*400 + q*100];
        float s = 0.f;
        for (int l = 0; l < 100; ++l) s += js[l] * betas[q*100 + l];
        s += __shfl_down(s, 15);
        s += __shfl_down(s, 30);
        if (q == 0) joints[j][kk] = s + baseJ[o];
    }
    if (tid < NJOINT) {
        int j = tid;
        float r[3];
        for (int c = 0; c < 3; ++c) {
            if (j == 0)      r[c] = ldf(grot, b*3 + c, f32);
            else if (j == 1) r[c] = ldf(neck, b*3 + c, f32);
            else if (j == 2) r[c] = ldf(jaw,  b*3 + c, f32);
            else if (j == 3) r[c] = ldf(eye,  b*6 + c, f32);
            else             r[c] = ldf(eye,  b*6 + 3 + c, f32);
        }
        float a0 = r[0] + 1e-8f, a1 = r[1] + 1e-8f, a2 = r[2] + 1e-8f;
        float angle = sqrtf(a0*a0 + a1*a1 + a2*a2);
        float inv = 1.0f / angle;
        float rx = r[0]*inv, ry = r[1]*inv, rz = r[2]*inv;
        float s = sinf(angle), c = cosf(angle);
        float K[9] = {0.f, -rz, ry,  rz, 0.f, -rx,  -ry, rx, 0.f};
        float K2[9];
        for (int rr = 0; rr < 3; ++rr)
            for (int cc = 0; cc < 3; ++cc) {
                float t = 0.f;
                for (int m = 0; m < 3; ++m) t += K[rr*3+m] * K[m*3+cc];
                K2[rr*3+cc] = t;
            }
        for (int i2 = 0; i2 < 9; ++i2) {
            float id = (i2 == 0 || i2 == 4 || i2 == 8) ? 1.f : 0.f;
            Rm[j][i2] = id + s*K[i2] + (1.f - c)*K2[i2];
        }
    }
    __syncthreads();

    if (tid < 36) {
        int i = tid / 9 + 1, rc = tid - (tid/9)*9;
        float id = (rc == 0 || rc == 4 || rc == 8) ? 1.f : 0.f;
        Act[act2_off(b, 400 + tid)] = __float2bfloat16(Rm[i][rc] - id);
    }
    if (tid == 0) {
        for (int rr = 0; rr < 3; ++rr) {
            for (int cc = 0; cc < 3; ++cc) Gm[0][rr*4+cc] = Rm[0][rr*3+cc];
            Gm[0][rr*4+3] = joints[0][rr];
        }
        const int par[NJOINT] = {-1, 0, 1, 1, 1};
        for (int j = 1; j < NJOINT; ++j) {
            int p = par[j];
            float rel[3];
            for (int c2 = 0; c2 < 3; ++c2) rel[c2] = joints[j][c2] - joints[p][c2];
            for (int rr = 0; rr < 3; ++rr) {
                for (int cc = 0; cc < 3; ++cc) {
                    float t = 0.f;
                    for (int m = 0; m < 3; ++m) t += Gm[p][rr*4+m] * Rm[j][m*3+cc];
                    Gm[j][rr*4+cc] = t;
                }
                float t = Gm[p][rr*4+3];
                for (int m = 0; m < 3; ++m) t += Gm[p][rr*4+m] * rel[m];
                Gm[j][rr*4+3] = t;
            }
        }
    }
    __syncthreads();

    if (tid < 60) {
        int j = tid / 12, e = tid - j*12, rr = e / 4, cc = e - rr*4;
        float val = Gm[j][e];
        if (cc == 3)
            for (int m = 0; m < 3; ++m) val -= Gm[j][rr*4+m] * joints[j][m];
        Amat[b*60 + tid] = val;
    }

    float part = 0.f;
    for (int i = tid; i < 400; i += 64) part += betas[i]*betas[i];
    part *= 0.001f;
    if (tid == 0) {
        float nn = 0.f, jj = 0.f;
        for (int c = 0; c < 3; ++c) {
            float nv = ldf(neck, b*3+c, f32);
            float jv = ldf(jaw,  b*3+c, f32);
            nn += nv*nv; jj += jv*jv;
        }
        part += 100.f*nn + 0.001f*jj;
    }
    for (int off = 32; off; off >>= 1) part += __shfl_down(part, off);
    if (tid == 0) atomicAdd(reg, part);
}

// Fused GEMM + LBS, tile-split, fragment-linear operands, BARRIER-FREE K-loop:
//  - each wave loads its 5 fragments/step DIRECTLY from global (coalesced
//    1KiB per load, 1 transaction) into named regs -> MFMA. No LDS staging,
//    no __syncthreads in the K-loop -> no lockstep, latency hidden by TLP.
//    (r4 lesson: per-step barrier+vmcnt drain+56KiB/step LDS round-trip
//    lockstepped 16 waves at ~4.6k cy/step. Fragment sharing now rides L2:
//    ~708 MB L2 reads total ~ 21 us floor, fully overlapped.)
//  - LDS 44.8 KB (epilogue only) -> 3 blocks/CU; launch_bounds(512,6)
//    caps VGPR at 85 (live set ~60) for 24 waves/CU TLP.
__global__ __launch_bounds__(512, 6) void k_gemm_lbs_big(
        const __hip_bfloat16* __restrict__ Act,
        const __hip_bfloat16* __restrict__ Wb,
        const void* __restrict__ v_template,
        const float* __restrict__ Amat,
        const void* __restrict__ weights,
        const void* __restrict__ transl,
        const void* __restrict__ shape_p,
        void* __restrict__ out) {
    __shared__ float chunk[8][16 * CH_S];   // 26.6 KB, per-wave
    __shared__ float Al[GBM * 60];          // 15.4 KB
    __shared__ float wl[64 * 5];            // 1.25 KB
    __shared__ float tl[GBM * 3];           // 0.75 KB
    __shared__ float vtl[GBN];              // 0.75 KB

    int f32 = probe_f32(shape_p);
    int tid = threadIdx.x;
    int wave = tid >> 6, lane = tid & 63;
    int fr = lane & 15, quad = lane >> 4;
    int mg = wave >> 2, wn = wave & 3;      // 2M x 4N wave grid

    // swizzle: panel P's 16 m-blocks all map to XCD P%8 (round-robin assumption)
    int lin = blockIdx.x;
    int xcd = lin & 7, slot = lin >> 3;
    int P = (slot >> 4) * 8 + xcd;
    int mblk = slot & 15;
    if (P >= GNP) return;
    int m0 = mblk * GBM;
    int n0 = P * GBN;
    int v0 = P * 64;

    // cooperative staging (consumed after the first epilogue barrier)
    for (int i = tid; i < GBM*60/4; i += 512)
        ((float4v*)Al)[i] = ((const float4v*)(Amat + (long)m0*60))[i];
    if (tid < 320) {
        int v = v0 + tid / 5;
        wl[tid] = (v < NV) ? ldf(weights, v*5 + tid % 5, f32) : 0.f;
    }
    if (tid < GBM*3)
        tl[tid] = ldf(transl, (long)m0*3 + tid, f32);
    if (tid >= 320) {
        int i = tid - 320;                  // 0..191
        vtl[i] = ((long)v0*3 + i < N3) ? ldf(v_template, (long)v0*3 + i, f32) : 0.f;
    }

    // fragment-linear base pointers: fragment (R,s) at (R*14+s)*512 elems,
    // this lane's 8 elems at +lane*8.
    int Ra = mblk*4 + mg*2;
    const __hip_bfloat16* aF0 = Act + (long)Ra * NSTEP * FRAG + lane*8;
    const __hip_bfloat16* aF1 = aF0 + (long)NSTEP * FRAG;
    const __hip_bfloat16* bF0;
    const __hip_bfloat16* bF1;
    const __hip_bfloat16* bF2;
    {
        int r0 = P*12 + wn*3;
        int r1 = r0 + 1, r2 = r0 + 2;
        if (r0 >= RB_B) r0 = RB_B - 1;      // OOB tail rows: garbage, never stored
        if (r1 >= RB_B) r1 = RB_B - 1;
        if (r2 >= RB_B) r2 = RB_B - 1;
        bF0 = Wb + (long)r0 * NSTEP * FRAG + lane*8;
        bF1 = Wb + (long)r1 * NSTEP * FRAG + lane*8;
        bF2 = Wb + (long)r2 * NSTEP * FRAG + lane*8;
    }

    floatx4 acc[2][3];
#pragma unroll
    for (int q = 0; q < 2; ++q)
#pragma unroll
        for (int t = 0; t < 3; ++t) acc[q][t] = (floatx4){0.f,0.f,0.f,0.f};

    // barrier-free K loop: 5 independent coalesced loads then 6 MFMAs per step
#pragma unroll
    for (int s = 0; s < NSTEP; ++s) {
        long o = (long)s * FRAG;
        short8 a0 = *(const short8*)(aF0 + o);
        short8 a1 = *(const short8*)(aF1 + o);
        short8 b0 = *(const short8*)(bF0 + o);
        short8 b1 = *(const short8*)(bF1 + o);
        short8 b2 = *(const short8*)(bF2 + o);
        acc[0][0] = __builtin_amdgcn_mfma_f32_16x16x32_bf16(a0, b0, acc[0][0], 0, 0, 0);
        acc[0][1] = __builtin_amdgcn_mfma_f32_16x16x32_bf16(a0, b1, acc[0][1], 0, 0, 0);
        acc[0][2] = __builtin_amdgcn_mfma_f32_16x16x32_bf16(a0, b2, acc[0][2], 0, 0, 0);
        acc[1][0] = __builtin_amdgcn_mfma_f32_16x16x32_bf16(a1, b0, acc[1][0], 0, 0, 0);
        acc[1][1] = __builtin_amdgcn_mfma_f32_16x16x32_bf16(a1, b1, acc[1][1], 0, 0, 0);
        acc[1][2] = __builtin_amdgcn_mfma_f32_16x16x32_bf16(a1, b2, acc[1][2], 0, 0, 0);
    }

    // epilogue: 2 chunks of 16 m-rows per wave; per-wave LDS buffer
    float* ch = chunk[wave];
    int mloc = lane >> 2, vq = lane & 3;    // 16 m x 4 vert-groups per chunk
#pragma unroll
    for (int q = 0; q < 2; ++q) {
#pragma unroll
        for (int t = 0; t < 3; ++t)
#pragma unroll
            for (int rr = 0; rr < 4; ++rr)
                ch[(quad*4 + rr)*CH_S + t*16 + fr] = acc[q][t][rr];
        __syncthreads();
        int mb = mg*32 + q*16 + mloc;       // block-local m
        long mglob = m0 + mb;
        const float* A = &Al[mb*60];
        float t0c = tl[mb*3+0], t1c = tl[mb*3+1], t2c = tl[mb*3+2];
        long obase = (mglob*NV + v0)*3;
#pragma unroll
        for (int vi = 0; vi < 4; ++vi) {
            int vloc = wn*16 + vq*4 + vi;   // block-local vertex 0..63
            int v = v0 + vloc;
            if (v < NV) {
                int o = mloc*CH_S + (vq*4 + vi)*3;
                float p0 = ch[o+0] + vtl[vloc*3 + 0];
                float p1 = ch[o+1] + vtl[vloc*3 + 1];
                float p2 = ch[o+2] + vtl[vloc*3 + 2];
                float w0 = wl[vloc*5+0], w1 = wl[vloc*5+1], w2 = wl[vloc*5+2];
                float w3 = wl[vloc*5+3], w4 = wl[vloc*5+4];
#pragma unroll
                for (int c = 0; c < 3; ++c) {
                    float t0 = w0*A[c*4+0] + w1*A[12+c*4+0] + w2*A[24+c*4+0] + w3*A[36+c*4+0] + w4*A[48+c*4+0];
                    float t1 = w0*A[c*4+1] + w1*A[12+c*4+1] + w2*A[24+c*4+1] + w3*A[36+c*4+1] + w4*A[48+c*4+1];
                    float t2 = w0*A[c*4+2] + w1*A[12+c*4+2] + w2*A[24+c*4+2] + w3*A[36+c*4+2] + w4*A[48+c*4+2];
                    float t3 = w0*A[c*4+3] + w1*A[12+c*4+3] + w2*A[24+c*4+3] + w3*A[36+c*4+3] + w4*A[48+c*4+3];
                    float tlc = (c == 0) ? t0c : ((c == 1) ? t1c : t2c);
                    float val = t0*p0 + t1*p1 + t2*p2 + t3 + tlc;
                    stf(out, obase + vloc*3 + c, val, f32);
                }
            }
        }
        __syncthreads();                    // chunk buffer reused next q
    }
}

// Fallback (small ws): register-direct from raw inputs; Act is fragment-linear.
__global__ __launch_bounds__(256) void k_gemm_lbs_small(
        const __hip_bfloat16* __restrict__ Act,
        const void* __restrict__ shapedirs,
        const void* __restrict__ posedirs,
        const void* __restrict__ v_template,
        const float* __restrict__ Amat,
        const void* __restrict__ weights,
        const void* __restrict__ transl,
        const int* __restrict__ flags,
        void* __restrict__ out) {
    __shared__ float tileS[4][16*49 + 4];
    __shared__ float AlS[4][960];
    __shared__ float wl[80];
    __shared__ __align__(16) __hip_bfloat16 Bs2[BN * 64];

    int f32 = flags[0];
    int tid = threadIdx.x;
    int wave = tid >> 6, lane = tid & 63;
    int fr = lane & 15, quad = lane >> 4;
    int m0 = blockIdx.x * 256;
    int n0 = blockIdx.y * BN;
    int v0 = blockIdx.y * 16;

    if (tid < 80) {
        int v = v0 + tid / 5;
        wl[tid] = (v < NV) ? ldf(weights, v*5 + tid % 5, f32) : 0.f;
    }
    for (int i = tid; i < BN * 64; i += 256) {
        int n = i >> 6, kk = i & 63;
        int nc = min(n0 + n, N3 - 1);
        float val = 0.f;
        if (kk < 16)      val = ldf(shapedirs, (long)nc*KBETA + 384 + kk, f32);
        else if (kk < 52) val = ldf(posedirs, (long)(kk-16)*N3 + nc, f32);
        Bs2[n*64 + kk] = __float2bfloat16(val);
    }
    __syncthreads();

    int Ra0 = (m0 >> 4) + wave*4;
    int nr[3];
#pragma unroll
    for (int t = 0; t < 3; ++t) nr[t] = min(n0 + t*16 + fr, N3 - 1);

    floatx4 acc[4][3];
#pragma unroll
    for (int sub = 0; sub < 4; ++sub)
#pragma unroll
        for (int t = 0; t < 3; ++t) acc[sub][t] = (floatx4){0.f,0.f,0.f,0.f};

#pragma unroll
    for (int s = 0; s < 14; ++s) {
        short8 bb[3];
#pragma unroll
        for (int t = 0; t < 3; ++t) {
            if (s < 12) bb[t] = ld8bf(shapedirs, (long)nr[t]*KBETA + s*32 + quad*8, f32);
            else        bb[t] = *(short8*)&Bs2[(t*16 + fr)*64 + (s-12)*32 + quad*8];
        }
#pragma unroll
        for (int sub = 0; sub < 4; ++sub) {
            short8 a = *(const short8*)(Act + (((long)(Ra0 + sub)*NSTEP + s)*64 + lane)*8);
#pragma unroll
            for (int t = 0; t < 3; ++t)
                acc[sub][t] = __builtin_amdgcn_mfma_f32_16x16x32_bf16(a, bb[t], acc[sub][t], 0, 0, 0);
        }
    }

    int vloc = fr, rgrp = quad;
    int v = v0 + vloc;
    float tpl0 = 0.f, tpl1 = 0.f, tpl2 = 0.f;
    if (v < NV) {
        tpl0 = ldf(v_template, v*3 + 0, f32);
        tpl1 = ldf(v_template, v*3 + 1, f32);
        tpl2 = ldf(v_template, v*3 + 2, f32);
    }
    float w0 = wl[vloc*5+0], w1 = wl[vloc*5+1], w2 = wl[vloc*5+2];
    float w3 = wl[vloc*5+3], w4 = wl[vloc*5+4];
    for (int sub = 0; sub < 4; ++sub) {
#pragma unroll
        for (int t = 0; t < 3; ++t)
#pragma unroll
            for (int rr = 0; rr < 4; ++rr)
                tileS[wave][(quad*4 + rr)*49 + t*16 + fr] = acc[sub][t][rr];
        for (int i = lane; i < 960; i += 64)
            AlS[wave][i] = Amat[(long)(m0 + wave*64 + sub*16)*60 + i];
        __syncthreads();
        if (v < NV) {
#pragma unroll
            for (int rr = 0; rr < 4; ++rr) {
                int mloc = rgrp*4 + rr;
                long m = m0 + wave*64 + sub*16 + mloc;
                float p0 = tileS[wave][mloc*49 + vloc*3 + 0] + tpl0;
                float p1 = tileS[wave][mloc*49 + vloc*3 + 1] + tpl1;
                float p2 = tileS[wave][mloc*49 + vloc*3 + 2] + tpl2;
                const float* A = &AlS[wave][mloc*60];
#pragma unroll
                for (int c = 0; c < 3; ++c) {
                    float t0 = w0*A[c*4+0] + w1*A[12+c*4+0] + w2*A[24+c*4+0] + w3*A[36+c*4+0] + w4*A[48+c*4+0];
                    float t1 = w0*A[c*4+1] + w1*A[12+c*4+1] + w2*A[24+c*4+1] + w3*A[36+c*4+1] + w4*A[48+c*4+1];
                    float t2 = w0*A[c*4+2] + w1*A[12+c*4+2] + w2*A[24+c*4+2] + w3*A[36+c*4+2] + w4*A[48+c*4+2];
                    float t3 = w0*A[c*4+3] + w1*A[12+c*4+3] + w2*A[24+c*4+3] + w3*A[36+c*4+3] + w4*A[48+c*4+3];
                    float val = t0*p0 + t1*p1 + t2*p2 + t3 + ldf(transl, m*3 + c, f32);
                    stf(out, (m*NV + v)*3 + c, val, f32);
                }
            }
        }
        __syncthreads();
    }
}

__global__ __launch_bounds__(64) void k_lmk(const void* __restrict__ verts,
                                            const void* __restrict__ bary,
                                            const int* __restrict__ faces,
                                            const void* __restrict__ lmk_idx,
                                            const void* __restrict__ transl,
                                            const float* __restrict__ reg,
                                            const void* __restrict__ shape_p,
                                            void* __restrict__ out) {
    int f32 = probe_f32(shape_p);
    int i64 = probe_i64(lmk_idx);
    int b = blockIdx.x, tid = threadIdx.x;
    if (b == 0 && tid == 63)
        stf(out, (long)BATCH*NV*3 + (long)BATCH*NLMK*3, reg[0], f32);
    if (tid >= NLMK) return;
    int f = i64 ? (int)((const long long*)lmk_idx)[tid]
                : ((const int*)lmk_idx)[tid];
    float acc[3] = {0.f, 0.f, 0.f};
    float bsum = 0.f;
    for (int fi = 0; fi < 3; ++fi) {
        int vi = faces[f*3 + fi];
        float bc = ldf(bary, tid*3 + fi, f32);
        bsum += bc;
#pragma unroll
        for (int c = 0; c < 3; ++c)
            acc[c] += bc * ldf(verts, ((long)b*NV + vi)*3 + c, f32);
    }
#pragma unroll
    for (int c = 0; c < 3; ++c) {
        float val = acc[c] + (1.f - bsum) * ldf(transl, b*3 + c, f32);
        stf(out, (long)BATCH*NV*3 + ((long)b*NLMK + tid)*3 + c, val, f32);
    }
}

extern "C" void kernel_launch(void* const* d_in, const int* in_sizes, int n_in,
                              void* d_out, int out_size, void* d_ws, size_t ws_size,
                              hipStream_t stream) {
    const void* shape_p   = d_in[0];
    const void* expr_p    = d_in[1];
    const void* grot      = d_in[2];
    const void* neck      = d_in[3];
    const void* jaw       = d_in[4];
    const void* eye       = d_in[5];
    const void* transl    = d_in[6];
    const void* v_templ   = d_in[7];
    const void* shapedirs = d_in[8];
    const void* posedirs  = d_in[9];
    const void* Jreg      = d_in[10];
    const void* weights   = d_in[11];
    const void* bary      = d_in[12];
    const int*  faces     = (const int*)d_in[14];
    const void* lmk_idx   = d_in[15];

    char* ws = (char*)d_ws;
    float* JS      = (float*)(ws + WS_JS);
    float* baseJ   = (float*)(ws + WS_BASEJ);
    float* reg     = (float*)(ws + WS_REG);
    int*   flags   = (int*)(ws + WS_FLAGS);
    float* Amat    = (float*)(ws + WS_AMAT);
    __hip_bfloat16* Act = (__hip_bfloat16*)(ws + WS_ACT);
    __hip_bfloat16* Wb  = (__hip_bfloat16*)(ws + WS_WB);
    float* PART    = (float*)d_out;   // scratch before verts are written
    bool big = ws_size >= (size_t)WS_FULL;

    if (big) {
        k_prep<<<CVT_BLKS + 384, 256, 0, stream>>>(shapedirs, posedirs, Jreg, v_templ,
                                                   shape_p, reg, Wb, PART);
        k_js_red<<<24, 256, 0, stream>>>(PART, JS, baseJ);
    } else {
        k_init<<<24, 256, 0, stream>>>((float*)ws, shape_p, lmk_idx, flags);
        k_js_atomic<<<dim3(3, 64), 256, 0, stream>>>(Jreg, shapedirs, v_templ, flags, JS, baseJ);
    }
    k_batch<<<BATCH, 64, 0, stream>>>(shape_p, expr_p, grot, neck, jaw, eye,
                                      JS, baseJ, Act, Amat, reg);
    if (big) {
        // swizzled 1D grid: 10 panel-groups * 8 xcd * 16 m = 1280 (16 no-ops)
        k_gemm_lbs_big<<<GGRID, 512, 0, stream>>>(Act, Wb, v_templ, Amat,
                                                  weights, transl, shape_p, d_out);
    } else {
        dim3 grid(BATCH/256, (N3 + BN - 1)/BN);
        k_gemm_lbs_small<<<grid, 256, 0, stream>>>(Act, shapedirs, posedirs, v_templ,
                                                   Amat, weights, transl, flags, d_out);
    }
    k_lmk<<<BATCH, 64, 0, stream>>>(d_out, bary, faces, lmk_idx, transl, reg, shape_p, d_out);
}

// Round 6
// 263.178 us; speedup vs baseline: 1.0381x; 1.0381x over previous
//
#include <hip/hip_runtime.h>
#include <hip/hip_bf16.h>

#define BATCH 1024
#define NV 5023
#define NJOINT 5
#define NLMK 51
#define N3 (NV*3)        // 15069
#define NPADB 15072      // N3 padded to multiple of 48 (and of 16)
#define KBETA 400
#define KTOT 448         // 400 betas + 36 pose_feature + 12 zero pad
#define NSTEP 14         // KTOT/32 MFMA k-steps
#define RB_B (NPADB/16)  // 942 row-blocks in Wb
#define RB_A 64          // 1024/16 row-blocks in Act
#define FRAG 512         // elems per (s,R) fragment: 64 lanes * 8 bf16

#define BM 64            // batches per block (small path)
#define BN 48            // output cols per block = 16 vertices (small path)
#define NVC 128          // v-chunks for js_part
#define CVT_BLKS 3297    // 844032 16B-chunks / 256

// big-path GEMM geometry: tile-split, no inter-wave reduction
#define GBM 64           // batches per block
#define GBN 192          // output cols per block = 64 vertices
#define GNP 79           // ceil(5023/64) panels
#define GGRID 1280       // ceil(79/8)*8 * 16 m-blocks
#define CH_S 52          // chunk stride (floats): 4*52 % 32 == 16 -> 2-way = free

typedef __attribute__((ext_vector_type(8))) short short8;
typedef __attribute__((ext_vector_type(4))) float floatx4;
typedef __attribute__((ext_vector_type(4))) float float4v;

// async global->LDS DMA, 16B per lane: LDS dest = uniform base + lane*16,
// global src = per-lane pointer. Counted by vmcnt.
#define GLDS16(gp, lp) \
    __builtin_amdgcn_global_load_lds( \
        (const __attribute__((address_space(1))) void*)(gp), \
        (__attribute__((address_space(3))) void*)(lp), 16, 0, 0)

// ---------------- workspace byte offsets ----------------
#define WS_JS      0          // 6000 f32
#define WS_BASEJ   24064      // 15 f32
#define WS_REG     24512      // 1 f32
#define WS_FLAGS   24520      // 2 ints (fallback path only)
#define WS_AMAT    24576      // 1024*60 f32   -> ends 270336
#define WS_ACT     270336     // 1024*448 bf16 (step-major frag-linear) -> ends 1187840
#define WS_WB      1187840    // 15072*448 bf16 (step-major frag-linear) -> ends 14692352
#define WS_FULL    14692352

__device__ __forceinline__ float ldf(const void* p, long i, int f32) {
    if (f32) return ((const float*)p)[i];
    return __bfloat162float(((const __hip_bfloat16*)p)[i]);
}
__device__ __forceinline__ short8 ld8bf(const void* p, long i, int f32) {
    if (f32) {
        // vectorized: two float4 loads (callers guarantee 16B alignment)
        float4v a = *(const float4v*)((const float*)p + i);
        float4v b = *(const float4v*)((const float*)p + i + 4);
        short8 r;
#pragma unroll
        for (int j = 0; j < 4; ++j) {
            __hip_bfloat16 h = __float2bfloat16(a[j]);
            r[j] = *reinterpret_cast<short*>(&h);
        }
#pragma unroll
        for (int j = 0; j < 4; ++j) {
            __hip_bfloat16 h = __float2bfloat16(b[j]);
            r[4 + j] = *reinterpret_cast<short*>(&h);
        }
        return r;
    }
    return *(const short8*)((const __hip_bfloat16*)p + i);
}
__device__ __forceinline__ void stf(void* p, long i, float v, int f32) {
    if (f32) ((float*)p)[i] = v;
    else ((__hip_bfloat16*)p)[i] = __float2bfloat16(v);
}

// step-major fragment-linear Act index: element (batch-row b, k) -> bf16 offset.
// fragment (s = k>>5, Ra = b>>4) is 512 contiguous elems at (s*RB_A + Ra)*512;
// lane quad = (k>>3)&3, fr = b&15, elem e = k&7.
__device__ __forceinline__ long act2_off(int b, int k) {
    return (((long)(k >> 5) * RB_A + (b >> 4)) * 64 + ((k >> 3) & 3) * 16 + (b & 15)) * 8 + (k & 7);
}

// per-wave inline dtype probe: f32 data read as bf16 halfwords blows past 1e4
__device__ __forceinline__ int probe_f32(const void* shape_p) {
    int lane = threadIdx.x & 63;
    unsigned short h = ((const unsigned short*)shape_p)[2 * lane];
    union { unsigned short u; __hip_bfloat16 b; } cv; cv.u = h;
    float v = fabsf(__bfloat162float(cv.b));
    if (v != v) v = 3.4e38f;
#pragma unroll
    for (int off = 32; off; off >>= 1) v = fmaxf(v, __shfl_down(v, off));
    v = __shfl(v, 0);
    return v > 1e4f;
}
__device__ __forceinline__ int probe_i64(const void* lmk_idx) {
    int lane = threadIdx.x & 63;
    const int* q = (const int*)lmk_idx;
    int odd_nonzero = (lane < 25) && (q[2*lane + 1] != 0);
    unsigned long long b = __ballot(odd_nonzero);
    return b == 0ull;
}

// fallback-path init: zero JS/baseJ/reg + write flags
__global__ void k_init(float* ws0, const void* shape_p, const void* lmk_idx, int* flags) {
    int i = blockIdx.x * 256 + threadIdx.x;
    if (i < 6129) ws0[i] = 0.f;
    if (blockIdx.x == 0 && threadIdx.x < 64) {
        int f = probe_f32(shape_p);
        int i64 = probe_i64(lmk_idx);
        if (threadIdx.x == 0) { flags[0] = f; flags[1] = i64; }
    }
}

// Fused prep (big path): blocks [0,CVT_BLKS) pack Wb in STEP-MAJOR
// fragment-linear layout (thread g writes contiguous 16B chunk #g);
// blocks [CVT_BLKS, +384) compute js partial sums from RAW shapedirs.
__global__ __launch_bounds__(256) void k_prep(const void* __restrict__ shapedirs,
                                              const void* __restrict__ posedirs,
                                              const void* __restrict__ Jreg,
                                              const void* __restrict__ v_template,
                                              const void* __restrict__ shape_p,
                                              float* __restrict__ reg,
                                              __hip_bfloat16* __restrict__ Wb,
                                              float* __restrict__ PART) {
    int f32 = probe_f32(shape_p);
    int blk = blockIdx.x, tid = threadIdx.x;
    if (blk < CVT_BLKS) {
        if (blk == 0 && tid == 0) reg[0] = 0.f;
        int g = blk * 256 + tid;          // chunk index < 844032
        int s = g / (RB_B * 64);          // 0..13
        int rem = g - s * (RB_B * 64);
        int R = rem >> 6;                 // 0..941
        int l = rem & 63;
        int quad = l >> 4, fr = l & 15;
        int n = R * 16 + fr;              // Wb row
        int k0 = s * 32 + quad * 8;       // first k of this 8-elem chunk
        short8 o;
#pragma unroll
        for (int e = 0; e < 8; ++e) o[e] = 0;
        if (n < N3) {
            if (k0 < KBETA) {
                o = ld8bf(shapedirs, (long)n * KBETA + k0, f32);
            } else if (k0 < 440) {
#pragma unroll
                for (int e = 0; e < 8; ++e) {
                    int kk = k0 + e - KBETA;
                    float val = (kk < 36) ? ldf(posedirs, (long)kk * N3 + n, f32) : 0.f;
                    __hip_bfloat16 h = __float2bfloat16(val);
                    o[e] = *reinterpret_cast<short*>(&h);
                }
            }
        }
        *(short8*)(Wb + (long)g * 8) = o;
    } else {
        int b2 = blk - CVT_BLKS;     // 0..383
        int k = b2 >> 7;             // 0..2
        int vc = b2 & 127;           // 0..127
        int v0 = vc * 40, v1 = min(NV, v0 + 40);
        int l2 = tid + 256;          // 400 == template col
        float acc1[NJOINT] = {0,0,0,0,0};
        float acc2[NJOINT] = {0,0,0,0,0};
        for (int v = v0; v < v1; ++v) {
            float s1 = ldf(shapedirs, (long)v*1200 + k*400 + tid, f32);
            float s2 = 0.f;
            if (l2 < 400)       s2 = ldf(shapedirs, (long)v*1200 + k*400 + l2, f32);
            else if (l2 == 400) s2 = ldf(v_template, v*3 + k, f32);
#pragma unroll
            for (int j = 0; j < NJOINT; ++j) {
                float jr = ldf(Jreg, j*NV + v, f32);
                acc1[j] += jr * s1;
                acc2[j] += jr * s2;
            }
        }
        long base = ((long)(k*NVC + vc)*5)*401;
#pragma unroll
        for (int j = 0; j < NJOINT; ++j) {
            PART[base + j*401 + tid] = acc1[j];
            if (l2 <= 400) PART[base + j*401 + l2] = acc2[j];
        }
    }
}

// Reduce over NVC chunks -> JS / baseJ.
__global__ __launch_bounds__(256) void k_js_red(const float* __restrict__ PART,
                                                float* __restrict__ JS,
                                                float* __restrict__ baseJ) {
    int o = blockIdx.x * 256 + threadIdx.x;
    if (o >= 3*5*401) return;
    int k = o / 2005, r = o - k*2005;
    int j = r / 401, l = r - j*401;
    float s = 0.f;
    long base = ((long)(k*NVC)*5 + j)*401 + l;
    for (int vc = 0; vc < NVC; ++vc) s += PART[base + (long)vc*2005];
    if (l < 400) JS[j*1200 + k*400 + l] = s;
    else         baseJ[j*3 + k] = s;
}

// Fallback JS (atomic, raw shapedirs) for small ws.
__global__ void k_js_atomic(const void* __restrict__ Jreg,
                            const void* __restrict__ shapedirs,
                            const void* __restrict__ v_template,
                            const int* __restrict__ flags,
                            float* __restrict__ JS, float* __restrict__ baseJ) {
    int f32 = flags[0];
    int k = blockIdx.x, vc = blockIdx.y, tid = threadIdx.x;
    int v0 = vc * 79, v1 = min(NV, v0 + 79);
    int l2 = tid + 256;
    float acc1[NJOINT] = {0,0,0,0,0};
    float acc2[NJOINT] = {0,0,0,0,0};
    for (int v = v0; v < v1; ++v) {
        float s1 = ldf(shapedirs, (long)v*1200 + k*400 + tid, f32);
        float s2 = 0.f;
        if (l2 < 400)       s2 = ldf(shapedirs, (long)v*1200 + k*400 + l2, f32);
        else if (l2 == 400) s2 = ldf(v_template, v*3 + k, f32);
#pragma unroll
        for (int j = 0; j < NJOINT; ++j) {
            float jr = ldf(Jreg, j*NV + v, f32);
            acc1[j] += jr * s1;
            acc2[j] += jr * s2;
        }
    }
#pragma unroll
    for (int j = 0; j < NJOINT; ++j) {
        atomicAdd(&JS[j*1200 + k*400 + tid], acc1[j]);
        if (l2 < 400)       atomicAdd(&JS[j*1200 + k*400 + l2], acc2[j]);
        else if (l2 == 400) atomicAdd(&baseJ[j*3 + k], acc2[j]);
    }
}

// Per-batch: betas->Act(bf16, step-major frag-linear), joints, rodrigues, chain, A, reg
__global__ __launch_bounds__(64) void k_batch(
        const void* __restrict__ shape_p, const void* __restrict__ expr_p,
        const void* __restrict__ grot, const void* __restrict__ neck,
        const void* __restrict__ jaw,  const void* __restrict__ eye,
        const float* __restrict__ JS, const float* __restrict__ baseJ,
        __hip_bfloat16* __restrict__ Act, float* __restrict__ Amat, float* __restrict__ reg) {
    int f32 = probe_f32(shape_p);
    int b = blockIdx.x, tid = threadIdx.x;
    __shared__ float betas[400];
    __shared__ float Rm[NJOINT][9];
    __shared__ float joints[NJOINT][3];
    __shared__ float Gm[NJOINT][12];

    for (int i = tid; i < 400; i += 64) {
        float v = (i < 300) ? ldf(shape_p, b*300 + i, f32)
                            : ldf(expr_p, b*100 + i - 300, f32);
        betas[i] = v;
        Act[act2_off(b, i)] = __float2bfloat16(v);
    }
    if (tid >= 36 && tid < 48) Act[act2_off(b, 400 + tid)] = __float2bfloat16(0.f);
    __syncthreads();

    if (tid < 60) {
        int o = tid % 15, q = tid / 15;
        int j = o / 3, kk = o - 3*j;
        const float* js = &JS[j*1200 + kk*400 + q*100];
        float s = 0.f;
        for (int l = 0; l < 100; ++l) s += js[l] * betas[q*100 + l];
        s += __shfl_down(s, 15);
        s += __shfl_down(s, 30);
        if (q == 0) joints[j][kk] = s + baseJ[o];
    }
    if (tid < NJOINT) {
        int j = tid;
        float r[3];
        for (int c = 0; c < 3; ++c) {
            if (j == 0)      r[c] = ldf(grot, b*3 + c, f32);
            else if (j == 1) r[c] = ldf(neck, b*3 + c, f32);
            else if (j == 2) r[c] = ldf(jaw,  b*3 + c, f32);
            else if (j == 3) r[c] = ldf(eye,  b*6 + c, f32);
            else             r[c] = ldf(eye,  b*6 + 3 + c, f32);
        }
        float a0 = r[0] + 1e-8f, a1 = r[1] + 1e-8f, a2 = r[2] + 1e-8f;
        float angle = sqrtf(a0*a0 + a1*a1 + a2*a2);
        float inv = 1.0f / angle;
        float rx = r[0]*inv, ry = r[1]*inv, rz = r[2]*inv;
        float s = sinf(angle), c = cosf(angle);
        float K[9] = {0.f, -rz, ry,  rz, 0.f, -rx,  -ry, rx, 0.f};
        float K2[9];
        for (int rr = 0; rr < 3; ++rr)
            for (int cc = 0; cc < 3; ++cc) {
                float t = 0.f;
                for (int m = 0; m < 3; ++m) t += K[rr*3+m] * K[m*3+cc];
                K2[rr*3+cc] = t;
            }
        for (int i2 = 0; i2 < 9; ++i2) {
            float id = (i2 == 0 || i2 == 4 || i2 == 8) ? 1.f : 0.f;
            Rm[j][i2] = id + s*K[i2] + (1.f - c)*K2[i2];
        }
    }
    __syncthreads();

    if (tid < 36) {
        int i = tid / 9 + 1, rc = tid - (tid/9)*9;
        float id = (rc == 0 || rc == 4 || rc == 8) ? 1.f : 0.f;
        Act[act2_off(b, 400 + tid)] = __float2bfloat16(Rm[i][rc] - id);
    }
    if (tid == 0) {
        for (int rr = 0; rr < 3; ++rr) {
            for (int cc = 0; cc < 3; ++cc) Gm[0][rr*4+cc] = Rm[0][rr*3+cc];
            Gm[0][rr*4+3] = joints[0][rr];
        }
        const int par[NJOINT] = {-1, 0, 1, 1, 1};
        for (int j = 1; j < NJOINT; ++j) {
            int p = par[j];
            float rel[3];
            for (int c2 = 0; c2 < 3; ++c2) rel[c2] = joints[j][c2] - joints[p][c2];
            for (int rr = 0; rr < 3; ++rr) {
                for (int cc = 0; cc < 3; ++cc) {
                    float t = 0.f;
                    for (int m = 0; m < 3; ++m) t += Gm[p][rr*4+m] * Rm[j][m*3+cc];
                    Gm[j][rr*4+cc] = t;
                }
                float t = Gm[p][rr*4+3];
                for (int m = 0; m < 3; ++m) t += Gm[p][rr*4+m] * rel[m];
                Gm[j][rr*4+3] = t;
            }
        }
    }
    __syncthreads();

    if (tid < 60) {
        int j = tid / 12, e = tid - j*12, rr = e / 4, cc = e - rr*4;
        float val = Gm[j][e];
        if (cc == 3)
            for (int m = 0; m < 3; ++m) val -= Gm[j][rr*4+m] * joints[j][m];
        Amat[b*60 + tid] = val;
    }

    float part = 0.f;
    for (int i = tid; i < 400; i += 64) part += betas[i]*betas[i];
    part *= 0.001f;
    if (tid == 0) {
        float nn = 0.f, jj = 0.f;
        for (int c = 0; c < 3; ++c) {
            float nv = ldf(neck, b*3+c, f32);
            float jv = ldf(jaw,  b*3+c, f32);
            nn += nv*nv; jj += jv*jv;
        }
        part += 100.f*nn + 0.001f*jj;
    }
    for (int off = 32; off; off >>= 1) part += __shfl_down(part, off);
    if (tid == 0) atomicAdd(reg, part);
}

// Fused GEMM + LBS, tile-split, step-major frag-linear operands,
// m97-style DMA pipeline (T3+T4):
//  - per K-step the block stages its UNIQUE 16KB tile (A 4KB + B 12KB,
//    both contiguous runs) via 16x global_load_lds (1KB per call, linear
//    lane*16 both sides). 283MB total through the load pipe vs 708MB of
//    per-wave redundant loads (r5's measured ~10-12 B/cy/CU wall).
//  - double-buffered, depth-2: issue stage(s+2) after barrier-2 of step s;
//    consume after counted vmcnt(2) + raw s_barrier (NEVER __syncthreads
//    in the loop -> no vmcnt(0) drain; T4).
//  - sched_barrier(0) fences around asm waits/barriers (guide lesson #18).
__global__ __launch_bounds__(512, 2) void k_gemm_lbs_big(
        const __hip_bfloat16* __restrict__ Act,
        const __hip_bfloat16* __restrict__ Wb,
        const void* __restrict__ v_template,
        const float* __restrict__ Amat,
        const void* __restrict__ weights,
        const void* __restrict__ transl,
        const void* __restrict__ shape_p,
        void* __restrict__ out) {
    __shared__ __align__(16) __hip_bfloat16 stage[2][16 * FRAG];  // 32 KB
    __shared__ float chunk[8][16 * CH_S];   // 26.6 KB, per-wave
    __shared__ float Al[GBM * 60];          // 15.4 KB
    __shared__ float wl[64 * 5];            // 1.25 KB
    __shared__ float tl[GBM * 3];           // 0.75 KB
    __shared__ float vtl[GBN];              // 0.75 KB

    int f32 = probe_f32(shape_p);
    int tid = threadIdx.x;
    int wave = tid >> 6, lane = tid & 63;
    int fr = lane & 15, quad = lane >> 4;
    int mg = wave >> 2, wn = wave & 3;      // 2M x 4N wave grid

    // swizzle: panel P's 16 m-blocks all map to XCD P%8 (round-robin assumption)
    int lin = blockIdx.x;
    int xcd = lin & 7, slot = lin >> 3;
    int P = (slot >> 4) * 8 + xcd;
    int mblk = slot & 15;
    if (P >= GNP) return;
    int m0 = mblk * GBM;
    int v0 = P * 64;

    // cooperative staging (consumed after the epilogue barriers)
    for (int i = tid; i < GBM*60/4; i += 512)
        ((float4v*)Al)[i] = ((const float4v*)(Amat + (long)m0*60))[i];
    if (tid < 320) {
        int v = v0 + tid / 5;
        wl[tid] = (v < NV) ? ldf(weights, v*5 + tid % 5, f32) : 0.f;
    }
    if (tid < GBM*3)
        tl[tid] = ldf(transl, (long)m0*3 + tid, f32);
    if (tid >= 320) {
        int i = tid - 320;                  // 0..191
        vtl[i] = ((long)v0*3 + i < N3) ? ldf(v_template, (long)v0*3 + i, f32) : 0.f;
    }

    // per-wave staging runs: wave w owns runs 2w, 2w+1 of 16 x 1KB.
    // runs 0..3 = A frags (s*RB_A + mblk*4 + r); runs 4..15 = B frags
    // (s*RB_B + P*12 + (r-4), clamped to last valid rb for the tail panel).
    int r0 = wave*2, r1 = wave*2 + 1;
    long aoff0 = 0, aoff1 = 0;              // frag offsets (without s term)
    const __hip_bfloat16* base0;
    const __hip_bfloat16* base1;
    int sstr0, sstr1;                       // per-step frag stride
    {
        // run r: A if r<4
        if (r0 < 4) { base0 = Act; sstr0 = RB_A; aoff0 = mblk*4 + r0; }
        else {
            long rb = (long)P*12 + (r0 - 4);
            if (rb > RB_B-1) rb = RB_B-1;
            base0 = Wb; sstr0 = RB_B; aoff0 = rb;
        }
        if (r1 < 4) { base1 = Act; sstr1 = RB_A; aoff1 = mblk*4 + r1; }
        else {
            long rb = (long)P*12 + (r1 - 4);
            if (rb > RB_B-1) rb = RB_B-1;
            base1 = Wb; sstr1 = RB_B; aoff1 = rb;
        }
    }
    __hip_bfloat16* lds0[2] = { &stage[0][r0*FRAG], &stage[1][r0*FRAG] };
    __hip_bfloat16* lds1[2] = { &stage[0][r1*FRAG], &stage[1][r1*FRAG] };

    floatx4 acc[2][3];
#pragma unroll
    for (int q = 0; q < 2; ++q)
#pragma unroll
        for (int t = 0; t < 3; ++t) acc[q][t] = (floatx4){0.f,0.f,0.f,0.f};

    // drain prologue loads so DMA vmcnt counting is deterministic
    asm volatile("s_waitcnt vmcnt(0)" ::: "memory");
    __builtin_amdgcn_sched_barrier(0);
    // prologue: stage steps 0 and 1 (2 DMA issues per wave per step)
    GLDS16(base0 + ((long)0*sstr0 + aoff0)*FRAG + lane*8, lds0[0]);
    GLDS16(base1 + ((long)0*sstr1 + aoff1)*FRAG + lane*8, lds1[0]);
    GLDS16(base0 + ((long)1*sstr0 + aoff0)*FRAG + lane*8, lds0[1]);
    GLDS16(base1 + ((long)1*sstr1 + aoff1)*FRAG + lane*8, lds1[1]);

#pragma unroll
    for (int s = 0; s < NSTEP; ++s) {
        const int cb = s & 1;
        // stage(s) complete: own 2 oldest of 4 outstanding (vmcnt(2));
        // last step has only 2 outstanding -> vmcnt(0)
        if (s == NSTEP-1) { asm volatile("s_waitcnt vmcnt(0)" ::: "memory"); }
        else              { asm volatile("s_waitcnt vmcnt(2)" ::: "memory"); }
        __builtin_amdgcn_sched_barrier(0);
        __builtin_amdgcn_s_barrier();       // all waves' stage(s) landed
        __builtin_amdgcn_sched_barrier(0);
        const __hip_bfloat16* sb = stage[cb];
        short8 a0 = *(const short8*)&sb[(mg*2 + 0)*FRAG + lane*8];
        short8 a1 = *(const short8*)&sb[(mg*2 + 1)*FRAG + lane*8];
        short8 b0 = *(const short8*)&sb[(4 + wn*3 + 0)*FRAG + lane*8];
        short8 b1 = *(const short8*)&sb[(4 + wn*3 + 1)*FRAG + lane*8];
        short8 b2 = *(const short8*)&sb[(4 + wn*3 + 2)*FRAG + lane*8];
        acc[0][0] = __builtin_amdgcn_mfma_f32_16x16x32_bf16(a0, b0, acc[0][0], 0, 0, 0);
        acc[0][1] = __builtin_amdgcn_mfma_f32_16x16x32_bf16(a0, b1, acc[0][1], 0, 0, 0);
        acc[0][2] = __builtin_amdgcn_mfma_f32_16x16x32_bf16(a0, b2, acc[0][2], 0, 0, 0);
        acc[1][0] = __builtin_amdgcn_mfma_f32_16x16x32_bf16(a1, b0, acc[1][0], 0, 0, 0);
        acc[1][1] = __builtin_amdgcn_mfma_f32_16x16x32_bf16(a1, b1, acc[1][1], 0, 0, 0);
        acc[1][2] = __builtin_amdgcn_mfma_f32_16x16x32_bf16(a1, b2, acc[1][2], 0, 0, 0);
        __builtin_amdgcn_sched_barrier(0);
        __builtin_amdgcn_s_barrier();       // all waves done reading buf cb
        __builtin_amdgcn_sched_barrier(0);
        if (s + 2 < NSTEP) {                // refill buf cb with step s+2
            GLDS16(base0 + ((long)(s+2)*sstr0 + aoff0)*FRAG + lane*8, lds0[cb]);
            GLDS16(base1 + ((long)(s+2)*sstr1 + aoff1)*FRAG + lane*8, lds1[cb]);
        }
    }

    // epilogue: 2 chunks of 16 m-rows per wave; per-wave LDS buffer
    __syncthreads();                        // full sync before LDS reuse pattern
    float* ch = chunk[wave];
    int mloc = lane >> 2, vq = lane & 3;    // 16 m x 4 vert-groups per chunk
#pragma unroll
    for (int q = 0; q < 2; ++q) {
#pragma unroll
        for (int t = 0; t < 3; ++t)
#pragma unroll
            for (int rr = 0; rr < 4; ++rr)
                ch[(quad*4 + rr)*CH_S + t*16 + fr] = acc[q][t][rr];
        __syncthreads();
        int mb = mg*32 + q*16 + mloc;       // block-local m
        long mglob = m0 + mb;
        const float* A = &Al[mb*60];
        float t0c = tl[mb*3+0], t1c = tl[mb*3+1], t2c = tl[mb*3+2];
        long obase = (mglob*NV + v0)*3;
#pragma unroll
        for (int vi = 0; vi < 4; ++vi) {
            int vloc = wn*16 + vq*4 + vi;   // block-local vertex 0..63
            int v = v0 + vloc;
            if (v < NV) {
                int o = mloc*CH_S + (vq*4 + vi)*3;
                float p0 = ch[o+0] + vtl[vloc*3 + 0];
                float p1 = ch[o+1] + vtl[vloc*3 + 1];
                float p2 = ch[o+2] + vtl[vloc*3 + 2];
                float w0 = wl[vloc*5+0], w1 = wl[vloc*5+1], w2 = wl[vloc*5+2];
                float w3 = wl[vloc*5+3], w4 = wl[vloc*5+4];
#pragma unroll
                for (int c = 0; c < 3; ++c) {
                    float t0 = w0*A[c*4+0] + w1*A[12+c*4+0] + w2*A[24+c*4+0] + w3*A[36+c*4+0] + w4*A[48+c*4+0];
                    float t1 = w0*A[c*4+1] + w1*A[12+c*4+1] + w2*A[24+c*4+1] + w3*A[36+c*4+1] + w4*A[48+c*4+1];
                    float t2 = w0*A[c*4+2] + w1*A[12+c*4+2] + w2*A[24+c*4+2] + w3*A[36+c*4+2] + w4*A[48+c*4+2];
                    float t3 = w0*A[c*4+3] + w1*A[12+c*4+3] + w2*A[24+c*4+3] + w3*A[36+c*4+3] + w4*A[48+c*4+3];
                    float tlc = (c == 0) ? t0c : ((c == 1) ? t1c : t2c);
                    float val = t0*p0 + t1*p1 + t2*p2 + t3 + tlc;
                    stf(out, obase + vloc*3 + c, val, f32);
                }
            }
        }
        __syncthreads();                    // chunk buffer reused next q
    }
}

// Fallback (small ws): register-direct from raw inputs; Act is step-major frag-linear.
__global__ __launch_bounds__(256) void k_gemm_lbs_small(
        const __hip_bfloat16* __restrict__ Act,
        const void* __restrict__ shapedirs,
        const void* __restrict__ posedirs,
        const void* __restrict__ v_template,
        const float* __restrict__ Amat,
        const void* __restrict__ weights,
        const void* __restrict__ transl,
        const int* __restrict__ flags,
        void* __restrict__ out) {
    __shared__ float tileS[4][16*49 + 4];
    __shared__ float AlS[4][960];
    __shared__ float wl[80];
    __shared__ __align__(16) __hip_bfloat16 Bs2[BN * 64];

    int f32 = flags[0];
    int tid = threadIdx.x;
    int wave = tid >> 6, lane = tid & 63;
    int fr = lane & 15, quad = lane >> 4;
    int m0 = blockIdx.x * 256;
    int n0 = blockIdx.y * BN;
    int v0 = blockIdx.y * 16;

    if (tid < 80) {
        int v = v0 + tid / 5;
        wl[tid] = (v < NV) ? ldf(weights, v*5 + tid % 5, f32) : 0.f;
    }
    for (int i = tid; i < BN * 64; i += 256) {
        int n = i >> 6, kk = i & 63;
        int nc = min(n0 + n, N3 - 1);
        float val = 0.f;
        if (kk < 16)      val = ldf(shapedirs, (long)nc*KBETA + 384 + kk, f32);
        else if (kk < 52) val = ldf(posedirs, (long)(kk-16)*N3 + nc, f32);
        Bs2[n*64 + kk] = __float2bfloat16(val);
    }
    __syncthreads();

    int Ra0 = (m0 >> 4) + wave*4;
    int nr[3];
#pragma unroll
    for (int t = 0; t < 3; ++t) nr[t] = min(n0 + t*16 + fr, N3 - 1);

    floatx4 acc[4][3];
#pragma unroll
    for (int sub = 0; sub < 4; ++sub)
#pragma unroll
        for (int t = 0; t < 3; ++t) acc[sub][t] = (floatx4){0.f,0.f,0.f,0.f};

#pragma unroll
    for (int s = 0; s < 14; ++s) {
        short8 bb[3];
#pragma unroll
        for (int t = 0; t < 3; ++t) {
            if (s < 12) bb[t] = ld8bf(shapedirs, (long)nr[t]*KBETA + s*32 + quad*8, f32);
            else        bb[t] = *(short8*)&Bs2[(t*16 + fr)*64 + (s-12)*32 + quad*8];
        }
#pragma unroll
        for (int sub = 0; sub < 4; ++sub) {
            short8 a = *(const short8*)(Act + (((long)s*RB_A + Ra0 + sub)*64 + lane)*8);
#pragma unroll
            for (int t = 0; t < 3; ++t)
                acc[sub][t] = __builtin_amdgcn_mfma_f32_16x16x32_bf16(a, bb[t], acc[sub][t], 0, 0, 0);
        }
    }

    int vloc = fr, rgrp = quad;
    int v = v0 + vloc;
    float tpl0 = 0.f, tpl1 = 0.f, tpl2 = 0.f;
    if (v < NV) {
        tpl0 = ldf(v_template, v*3 + 0, f32);
        tpl1 = ldf(v_template, v*3 + 1, f32);
        tpl2 = ldf(v_template, v*3 + 2, f32);
    }
    float w0 = wl[vloc*5+0], w1 = wl[vloc*5+1], w2 = wl[vloc*5+2];
    float w3 = wl[vloc*5+3], w4 = wl[vloc*5+4];
    for (int sub = 0; sub < 4; ++sub) {
#pragma unroll
        for (int t = 0; t < 3; ++t)
#pragma unroll
            for (int rr = 0; rr < 4; ++rr)
                tileS[wave][(quad*4 + rr)*49 + t*16 + fr] = acc[sub][t][rr];
        for (int i = lane; i < 960; i += 64)
            AlS[wave][i] = Amat[(long)(m0 + wave*64 + sub*16)*60 + i];
        __syncthreads();
        if (v < NV) {
#pragma unroll
            for (int rr = 0; rr < 4; ++rr) {
                int mloc = rgrp*4 + rr;
                long m = m0 + wave*64 + sub*16 + mloc;
                float p0 = tileS[wave][mloc*49 + vloc*3 + 0] + tpl0;
                float p1 = tileS[wave][mloc*49 + vloc*3 + 1] + tpl1;
                float p2 = tileS[wave][mloc*49 + vloc*3 + 2] + tpl2;
                const float* A = &AlS[wave][mloc*60];
#pragma unroll
                for (int c = 0; c < 3; ++c) {
                    float t0 = w0*A[c*4+0] + w1*A[12+c*4+0] + w2*A[24+c*4+0] + w3*A[36+c*4+0] + w4*A[48+c*4+0];
                    float t1 = w0*A[c*4+1] + w1*A[12+c*4+1] + w2*A[24+c*4+1] + w3*A[36+c*4+1] + w4*A[48+c*4+1];
                    float t2 = w0*A[c*4+2] + w1*A[12+c*4+2] + w2*A[24+c*4+2] + w3*A[36+c*4+2] + w4*A[48+c*4+2];
                    float t3 = w0*A[c*4+3] + w1*A[12+c*4+3] + w2*A[24+c*4+3] + w3*A[36+c*4+3] + w4*A[48+c*4+3];
                    float val = t0*p0 + t1*p1 + t2*p2 + t3 + ldf(transl, m*3 + c, f32);
                    stf(out, (m*NV + v)*3 + c, val, f32);
                }
            }
        }
        __syncthreads();
    }
}

__global__ __launch_bounds__(64) void k_lmk(const void* __restrict__ verts,
                                            const void* __restrict__ bary,
                                            const int* __restrict__ faces,
                                            const void* __restrict__ lmk_idx,
                                            const void* __restrict__ transl,
                                            const float* __restrict__ reg,
                                            const void* __restrict__ shape_p,
                                            void* __restrict__ out) {
    int f32 = probe_f32(shape_p);
    int i64 = probe_i64(lmk_idx);
    int b = blockIdx.x, tid = threadIdx.x;
    if (b == 0 && tid == 63)
        stf(out, (long)BATCH*NV*3 + (long)BATCH*NLMK*3, reg[0], f32);
    if (tid >= NLMK) return;
    int f = i64 ? (int)((const long long*)lmk_idx)[tid]
                : ((const int*)lmk_idx)[tid];
    float acc[3] = {0.f, 0.f, 0.f};
    float bsum = 0.f;
    for (int fi = 0; fi < 3; ++fi) {
        int vi = faces[f*3 + fi];
        float bc = ldf(bary, tid*3 + fi, f32);
        bsum += bc;
#pragma unroll
        for (int c = 0; c < 3; ++c)
            acc[c] += bc * ldf(verts, ((long)b*NV + vi)*3 + c, f32);
    }
#pragma unroll
    for (int c = 0; c < 3; ++c) {
        float val = acc[c] + (1.f - bsum) * ldf(transl, b*3 + c, f32);
        stf(out, (long)BATCH*NV*3 + ((long)b*NLMK + tid)*3 + c, val, f32);
    }
}

extern "C" void kernel_launch(void* const* d_in, const int* in_sizes, int n_in,
                              void* d_out, int out_size, void* d_ws, size_t ws_size,
                              hipStream_t stream) {
    const void* shape_p   = d_in[0];
    const void* expr_p    = d_in[1];
    const void* grot      = d_in[2];
    const void* neck      = d_in[3];
    const void* jaw       = d_in[4];
    const void* eye       = d_in[5];
    const void* transl    = d_in[6];
    const void* v_templ   = d_in[7];
    const void* shapedirs = d_in[8];
    const void* posedirs  = d_in[9];
    const void* Jreg      = d_in[10];
    const void* weights   = d_in[11];
    const void* bary      = d_in[12];
    const int*  faces     = (const int*)d_in[14];
    const void* lmk_idx   = d_in[15];

    char* ws = (char*)d_ws;
    float* JS      = (float*)(ws + WS_JS);
    float* baseJ   = (float*)(ws + WS_BASEJ);
    float* reg     = (float*)(ws + WS_REG);
    int*   flags   = (int*)(ws + WS_FLAGS);
    float* Amat    = (float*)(ws + WS_AMAT);
    __hip_bfloat16* Act = (__hip_bfloat16*)(ws + WS_ACT);
    __hip_bfloat16* Wb  = (__hip_bfloat16*)(ws + WS_WB);
    float* PART    = (float*)d_out;   // scratch before verts are written
    bool big = ws_size >= (size_t)WS_FULL;

    if (big) {
        k_prep<<<CVT_BLKS + 384, 256, 0, stream>>>(shapedirs, posedirs, Jreg, v_templ,
                                                   shape_p, reg, Wb, PART);
        k_js_red<<<24, 256, 0, stream>>>(PART, JS, baseJ);
    } else {
        k_init<<<24, 256, 0, stream>>>((float*)ws, shape_p, lmk_idx, flags);
        k_js_atomic<<<dim3(3, 64), 256, 0, stream>>>(Jreg, shapedirs, v_templ, flags, JS, baseJ);
    }
    k_batch<<<BATCH, 64, 0, stream>>>(shape_p, expr_p, grot, neck, jaw, eye,
                                      JS, baseJ, Act, Amat, reg);
    if (big) {
        // swizzled 1D grid: 10 panel-groups * 8 xcd * 16 m = 1280 (16 no-ops)
        k_gemm_lbs_big<<<GGRID, 512, 0, stream>>>(Act, Wb, v_templ, Amat,
                                                  weights, transl, shape_p, d_out);
    } else {
        dim3 grid(BATCH/256, (N3 + BN - 1)/BN);
        k_gemm_lbs_small<<<grid, 256, 0, stream>>>(Act, shapedirs, posedirs, v_templ,
                                                   Amat, weights, transl, flags, d_out);
    }
    k_lmk<<<BATCH, 64, 0, stream>>>(d_out, bary, faces, lmk_idx, transl, reg, shape_p, d_out);
}

// Round 7
// 254.468 us; speedup vs baseline: 1.0737x; 1.0342x over previous
//
#include <hip/hip_runtime.h>
#include <hip/hip_bf16.h>

#define BATCH 1024
#define NV 5023
#define NJOINT 5
#define NLMK 51
#define N3 (NV*3)        // 15069
#define NPADB 15072      // N3 padded to multiple of 48 (and of 16)
#define KBETA 400
#define KTOT 448         // 400 betas + 36 pose_feature + 12 zero pad
#define NSTEP 14         // KTOT/32 MFMA k-steps
#define RB_B (NPADB/16)  // 942 row-blocks in Wb
#define RB_A 64          // 1024/16 row-blocks in Act
#define FRAG 512         // elems per (s,R) fragment: 64 lanes * 8 bf16

#define BM 64            // batches per block (small path)
#define BN 48            // output cols per block = 16 vertices (small path)

// k_prep regions
#define PK_BETA_CH (NPADB*50)        // 753600 16B-chunks, read-linear
#define PK_BETA_BLKS 2944            // ceil(753600/256)
#define PK_POSE_CH (RB_B*96)         // 90432 chunks (k 384..448 minus beta part)
#define PK_POSE_BLKS 354             // ceil(90432/256)
#define NVC2 360                     // js v-chunks (14 verts each)
#define VCH 14
#define PK_JS_BLKS (3*NVC2)          // 1080

// big-path GEMM geometry: tile-split, no inter-wave reduction
#define GBM 64           // batches per block
#define GBN 192          // output cols per block = 64 vertices
#define GNP 79           // ceil(5023/64) panels
#define GGRID 1280       // ceil(79/8)*8 * 16 m-blocks
#define CH_S 52          // chunk stride (floats): 4*52 % 32 == 16 -> 2-way = free

typedef __attribute__((ext_vector_type(8))) short short8;
typedef __attribute__((ext_vector_type(4))) float floatx4;
typedef __attribute__((ext_vector_type(4))) float float4v;

// async global->LDS DMA, 16B per lane: LDS dest = uniform base + lane*16,
// global src = per-lane pointer. Counted by vmcnt.
#define GLDS16(gp, lp) \
    __builtin_amdgcn_global_load_lds( \
        (const __attribute__((address_space(1))) void*)(gp), \
        (__attribute__((address_space(3))) void*)(lp), 16, 0, 0)

// ---------------- workspace byte offsets ----------------
#define WS_JS      0          // 6000 f32
#define WS_BASEJ   24064      // 15 f32
#define WS_REG     24512      // 1 f32
#define WS_FLAGS   24520      // 2 ints (fallback path only)
#define WS_AMAT    24576      // 1024*60 f32   -> ends 270336
#define WS_ACT     270336     // 1024*448 bf16 (step-major frag-linear) -> ends 1187840
#define WS_WB      1187840    // 15072*448 bf16 (step-major frag-linear) -> ends 14692352
#define WS_FULL    14692352

__device__ __forceinline__ float ldf(const void* p, long i, int f32) {
    if (f32) return ((const float*)p)[i];
    return __bfloat162float(((const __hip_bfloat16*)p)[i]);
}
__device__ __forceinline__ short8 ld8bf(const void* p, long i, int f32) {
    if (f32) {
        // vectorized: two float4 loads (callers guarantee 16B alignment)
        float4v a = *(const float4v*)((const float*)p + i);
        float4v b = *(const float4v*)((const float*)p + i + 4);
        short8 r;
#pragma unroll
        for (int j = 0; j < 4; ++j) {
            __hip_bfloat16 h = __float2bfloat16(a[j]);
            r[j] = *reinterpret_cast<short*>(&h);
        }
#pragma unroll
        for (int j = 0; j < 4; ++j) {
            __hip_bfloat16 h = __float2bfloat16(b[j]);
            r[4 + j] = *reinterpret_cast<short*>(&h);
        }
        return r;
    }
    return *(const short8*)((const __hip_bfloat16*)p + i);
}
__device__ __forceinline__ void stf(void* p, long i, float v, int f32) {
    if (f32) ((float*)p)[i] = v;
    else ((__hip_bfloat16*)p)[i] = __float2bfloat16(v);
}

// step-major fragment-linear Act index: element (batch-row b, k) -> bf16 offset.
// fragment (s = k>>5, Ra = b>>4) is 512 contiguous elems at (s*RB_A + Ra)*512;
// lane quad = (k>>3)&3, fr = b&15, elem e = k&7.
__device__ __forceinline__ long act2_off(int b, int k) {
    return (((long)(k >> 5) * RB_A + (b >> 4)) * 64 + ((k >> 3) & 3) * 16 + (b & 15)) * 8 + (k & 7);
}

// per-wave inline dtype probe: f32 data read as bf16 halfwords blows past 1e4
__device__ __forceinline__ int probe_f32(const void* shape_p) {
    int lane = threadIdx.x & 63;
    unsigned short h = ((const unsigned short*)shape_p)[2 * lane];
    union { unsigned short u; __hip_bfloat16 b; } cv; cv.u = h;
    float v = fabsf(__bfloat162float(cv.b));
    if (v != v) v = 3.4e38f;
#pragma unroll
    for (int off = 32; off; off >>= 1) v = fmaxf(v, __shfl_down(v, off));
    v = __shfl(v, 0);
    return v > 1e4f;
}
__device__ __forceinline__ int probe_i64(const void* lmk_idx) {
    int lane = threadIdx.x & 63;
    const int* q = (const int*)lmk_idx;
    int odd_nonzero = (lane < 25) && (q[2*lane + 1] != 0);
    unsigned long long b = __ballot(odd_nonzero);
    return b == 0ull;
}

// fallback-path init: zero JS/baseJ/reg + write flags
__global__ void k_init(float* ws0, const void* shape_p, const void* lmk_idx, int* flags) {
    int i = blockIdx.x * 256 + threadIdx.x;
    if (i < 6129) ws0[i] = 0.f;
    if (blockIdx.x == 0 && threadIdx.x < 64) {
        int f = probe_f32(shape_p);
        int i64 = probe_i64(lmk_idx);
        if (threadIdx.x == 0) { flags[0] = f; flags[1] = i64; }
    }
}

// Fused prep (big path), three concurrent regions:
//  A) beta pack [0, PK_BETA_BLKS): thread g reads 8 CONTIGUOUS shapedirs
//     elems (row-linear, coalesced: 50 threads cover one 400-col row) and
//     writes one 16B chunk to the scattered frag-linear Wb slot. Scatter
//     moved from read side (latency-stalling, r6 and earlier) to write side
//     (fire-and-forget; adjacent rows assemble full lines in same-XCD L2).
//  B) pose pack: 16 lanes = 16 consecutive rows (coalesced posedirs column
//     reads), chunk writes coalesced.
//  C) js partials: NVC2=360 chunks of 14 verts (3x blocks of old), Jreg
//     cached in LDS, 2 coalesced row-loads per vert.
__global__ __launch_bounds__(256) void k_prep(const void* __restrict__ shapedirs,
                                              const void* __restrict__ posedirs,
                                              const void* __restrict__ Jreg,
                                              const void* __restrict__ v_template,
                                              const void* __restrict__ shape_p,
                                              float* __restrict__ reg,
                                              __hip_bfloat16* __restrict__ Wb,
                                              float* __restrict__ PART) {
    __shared__ float jl[NJOINT * VCH];
    int f32 = probe_f32(shape_p);
    int blk = blockIdx.x, tid = threadIdx.x;
    if (blk < PK_BETA_BLKS) {
        if (blk == 0 && tid == 0) reg[0] = 0.f;
        int g = blk * 256 + tid;
        if (g >= PK_BETA_CH) return;
        int n = g / 50, kg = g - n * 50;     // row n, k = kg*8 (contiguous read)
        short8 o;
#pragma unroll
        for (int e = 0; e < 8; ++e) o[e] = 0;
        if (n < N3) o = ld8bf(shapedirs, (long)n * KBETA + kg * 8, f32);
        long chunk = ((long)(kg >> 2) * RB_B + (n >> 4)) * 64 + (kg & 3) * 16 + (n & 15);
        *(short8*)(Wb + chunk * 8) = o;
    } else if (blk < PK_BETA_BLKS + PK_POSE_BLKS) {
        int g = (blk - PK_BETA_BLKS) * 256 + tid;
        if (g >= PK_POSE_CH) return;
        int R = g / 96, rem = g - R * 96;
        int c = rem >> 4, fr = rem & 15;     // c: 6 chunks covering k 400..447
        int n = R * 16 + fr;
        int k0 = KBETA + 8 * c;
        short8 o;
#pragma unroll
        for (int e = 0; e < 8; ++e) o[e] = 0;
        if (n < N3) {
#pragma unroll
            for (int e = 0; e < 8; ++e) {
                int kk = k0 + e - KBETA;
                float val = (kk < 36) ? ldf(posedirs, (long)kk * N3 + n, f32) : 0.f;
                __hip_bfloat16 h = __float2bfloat16(val);
                o[e] = *reinterpret_cast<short*>(&h);
            }
        }
        long chunk = ((long)(k0 >> 5) * RB_B + R) * 64 + ((k0 >> 3) & 3) * 16 + fr;
        *(short8*)(Wb + chunk * 8) = o;
    } else {
        int b2 = blk - (PK_BETA_BLKS + PK_POSE_BLKS);  // 0..1079
        int k = b2 / NVC2;                    // 0..2
        int vc = b2 - k * NVC2;               // 0..359
        int v0 = vc * VCH;
        if (tid < NJOINT * VCH) {
            int j = tid / VCH, i = tid - j * VCH;
            int v = min(v0 + i, NV - 1);
            jl[tid] = ldf(Jreg, (long)j * NV + v, f32);
        }
        __syncthreads();
        int l2 = tid + 256;                   // 400 == template col
        float acc1[NJOINT] = {0,0,0,0,0};
        float acc2[NJOINT] = {0,0,0,0,0};
#pragma unroll
        for (int i = 0; i < VCH; ++i) {
            int v = v0 + i;
            if (v >= NV) break;
            float s1 = ldf(shapedirs, (long)v*1200 + k*400 + tid, f32);
            float s2 = 0.f;
            if (l2 < 400)       s2 = ldf(shapedirs, (long)v*1200 + k*400 + l2, f32);
            else if (l2 == 400) s2 = ldf(v_template, v*3 + k, f32);
#pragma unroll
            for (int j = 0; j < NJOINT; ++j) {
                float jr = jl[j*VCH + i];
                acc1[j] += jr * s1;
                acc2[j] += jr * s2;
            }
        }
        long base = ((long)(k*NVC2 + vc)*5)*401;
#pragma unroll
        for (int j = 0; j < NJOINT; ++j) {
            PART[base + j*401 + tid] = acc1[j];
            if (l2 <= 400) PART[base + j*401 + l2] = acc2[j];
        }
    }
}

// Reduce over NVC2 chunks -> JS / baseJ.
__global__ __launch_bounds__(256) void k_js_red(const float* __restrict__ PART,
                                                float* __restrict__ JS,
                                                float* __restrict__ baseJ) {
    int o = blockIdx.x * 256 + threadIdx.x;
    if (o >= 3*5*401) return;
    int k = o / 2005, r = o - k*2005;
    int j = r / 401, l = r - j*401;
    float s = 0.f;
    long base = ((long)(k*NVC2)*5 + j)*401 + l;
    for (int vc = 0; vc < NVC2; ++vc) s += PART[base + (long)vc*2005];
    if (l < 400) JS[j*1200 + k*400 + l] = s;
    else         baseJ[j*3 + k] = s;
}

// Fallback JS (atomic, raw shapedirs) for small ws.
__global__ void k_js_atomic(const void* __restrict__ Jreg,
                            const void* __restrict__ shapedirs,
                            const void* __restrict__ v_template,
                            const int* __restrict__ flags,
                            float* __restrict__ JS, float* __restrict__ baseJ) {
    int f32 = flags[0];
    int k = blockIdx.x, vc = blockIdx.y, tid = threadIdx.x;
    int v0 = vc * 79, v1 = min(NV, v0 + 79);
    int l2 = tid + 256;
    float acc1[NJOINT] = {0,0,0,0,0};
    float acc2[NJOINT] = {0,0,0,0,0};
    for (int v = v0; v < v1; ++v) {
        float s1 = ldf(shapedirs, (long)v*1200 + k*400 + tid, f32);
        float s2 = 0.f;
        if (l2 < 400)       s2 = ldf(shapedirs, (long)v*1200 + k*400 + l2, f32);
        else if (l2 == 400) s2 = ldf(v_template, v*3 + k, f32);
#pragma unroll
        for (int j = 0; j < NJOINT; ++j) {
            float jr = ldf(Jreg, j*NV + v, f32);
            acc1[j] += jr * s1;
            acc2[j] += jr * s2;
        }
    }
#pragma unroll
    for (int j = 0; j < NJOINT; ++j) {
        atomicAdd(&JS[j*1200 + k*400 + tid], acc1[j]);
        if (l2 < 400)       atomicAdd(&JS[j*1200 + k*400 + l2], acc2[j]);
        else if (l2 == 400) atomicAdd(&baseJ[j*3 + k], acc2[j]);
    }
}

// Per-batch: betas->Act(bf16, step-major frag-linear), joints, rodrigues, chain, A, reg
__global__ __launch_bounds__(64) void k_batch(
        const void* __restrict__ shape_p, const void* __restrict__ expr_p,
        const void* __restrict__ grot, const void* __restrict__ neck,
        const void* __restrict__ jaw,  const void* __restrict__ eye,
        const float* __restrict__ JS, const float* __restrict__ baseJ,
        __hip_bfloat16* __restrict__ Act, float* __restrict__ Amat, float* __restrict__ reg) {
    int f32 = probe_f32(shape_p);
    int b = blockIdx.x, tid = threadIdx.x;
    __shared__ float betas[400];
    __shared__ float Rm[NJOINT][9];
    __shared__ float joints[NJOINT][3];
    __shared__ float Gm[NJOINT][12];

    for (int i = tid; i < 400; i += 64) {
        float v = (i < 300) ? ldf(shape_p, b*300 + i, f32)
                            : ldf(expr_p, b*100 + i - 300, f32);
        betas[i] = v;
        Act[act2_off(b, i)] = __float2bfloat16(v);
    }
    if (tid >= 36 && tid < 48) Act[act2_off(b, 400 + tid)] = __float2bfloat16(0.f);
    __syncthreads();

    if (tid < 60) {
        int o = tid % 15, q = tid / 15;
        int j = o / 3, kk = o - 3*j;
        const float* js = &JS[j*1200 + kk*400 + q*100];
        float s = 0.f;
        for (int l = 0; l < 100; ++l) s += js[l] * betas[q*100 + l];
        s += __shfl_down(s, 15);
        s += __shfl_down(s, 30);
        if (q == 0) joints[j][kk] = s + baseJ[o];
    }
    if (tid < NJOINT) {
        int j = tid;
        float r[3];
        for (int c = 0; c < 3; ++c) {
            if (j == 0)      r[c] = ldf(grot, b*3 + c, f32);
            else if (j == 1) r[c] = ldf(neck, b*3 + c, f32);
            else if (j == 2) r[c] = ldf(jaw,  b*3 + c, f32);
            else if (j == 3) r[c] = ldf(eye,  b*6 + c, f32);
            else             r[c] = ldf(eye,  b*6 + 3 + c, f32);
        }
        float a0 = r[0] + 1e-8f, a1 = r[1] + 1e-8f, a2 = r[2] + 1e-8f;
        float angle = sqrtf(a0*a0 + a1*a1 + a2*a2);
        float inv = 1.0f / angle;
        float rx = r[0]*inv, ry = r[1]*inv, rz = r[2]*inv;
        float s = sinf(angle), c = cosf(angle);
        float K[9] = {0.f, -rz, ry,  rz, 0.f, -rx,  -ry, rx, 0.f};
        float K2[9];
        for (int rr = 0; rr < 3; ++rr)
            for (int cc = 0; cc < 3; ++cc) {
                float t = 0.f;
                for (int m = 0; m < 3; ++m) t += K[rr*3+m] * K[m*3+cc];
                K2[rr*3+cc] = t;
            }
        for (int i2 = 0; i2 < 9; ++i2) {
            float id = (i2 == 0 || i2 == 4 || i2 == 8) ? 1.f : 0.f;
            Rm[j][i2] = id + s*K[i2] + (1.f - c)*K2[i2];
        }
    }
    __syncthreads();

    if (tid < 36) {
        int i = tid / 9 + 1, rc = tid - (tid/9)*9;
        float id = (rc == 0 || rc == 4 || rc == 8) ? 1.f : 0.f;
        Act[act2_off(b, 400 + tid)] = __float2bfloat16(Rm[i][rc] - id);
    }
    if (tid == 0) {
        for (int rr = 0; rr < 3; ++rr) {
            for (int cc = 0; cc < 3; ++cc) Gm[0][rr*4+cc] = Rm[0][rr*3+cc];
            Gm[0][rr*4+3] = joints[0][rr];
        }
        const int par[NJOINT] = {-1, 0, 1, 1, 1};
        for (int j = 1; j < NJOINT; ++j) {
            int p = par[j];
            float rel[3];
            for (int c2 = 0; c2 < 3; ++c2) rel[c2] = joints[j][c2] - joints[p][c2];
            for (int rr = 0; rr < 3; ++rr) {
                for (int cc = 0; cc < 3; ++cc) {
                    float t = 0.f;
                    for (int m = 0; m < 3; ++m) t += Gm[p][rr*4+m] * Rm[j][m*3+cc];
                    Gm[j][rr*4+cc] = t;
                }
                float t = Gm[p][rr*4+3];
                for (int m = 0; m < 3; ++m) t += Gm[p][rr*4+m] * rel[m];
                Gm[j][rr*4+3] = t;
            }
        }
    }
    __syncthreads();

    if (tid < 60) {
        int j = tid / 12, e = tid - j*12, rr = e / 4, cc = e - rr*4;
        float val = Gm[j][e];
        if (cc == 3)
            for (int m = 0; m < 3; ++m) val -= Gm[j][rr*4+m] * joints[j][m];
        Amat[b*60 + tid] = val;
    }

    float part = 0.f;
    for (int i = tid; i < 400; i += 64) part += betas[i]*betas[i];
    part *= 0.001f;
    if (tid == 0) {
        float nn = 0.f, jj = 0.f;
        for (int c = 0; c < 3; ++c) {
            float nv = ldf(neck, b*3+c, f32);
            float jv = ldf(jaw,  b*3+c, f32);
            nn += nv*nv; jj += jv*jv;
        }
        part += 100.f*nn + 0.001f*jj;
    }
    for (int off = 32; off; off >>= 1) part += __shfl_down(part, off);
    if (tid == 0) atomicAdd(reg, part);
}

// Fused GEMM + LBS (UNCHANGED from r6 — control for this round's A/B):
// tile-split, step-major frag-linear operands, DMA pipeline with counted
// vmcnt(2) + raw s_barrier.
__global__ __launch_bounds__(512, 2) void k_gemm_lbs_big(
        const __hip_bfloat16* __restrict__ Act,
        const __hip_bfloat16* __restrict__ Wb,
        const void* __restrict__ v_template,
        const float* __restrict__ Amat,
        const void* __restrict__ weights,
        const void* __restrict__ transl,
        const void* __restrict__ shape_p,
        void* __restrict__ out) {
    __shared__ __align__(16) __hip_bfloat16 stage[2][16 * FRAG];  // 32 KB
    __shared__ float chunk[8][16 * CH_S];   // 26.6 KB, per-wave
    __shared__ float Al[GBM * 60];          // 15.4 KB
    __shared__ float wl[64 * 5];            // 1.25 KB
    __shared__ float tl[GBM * 3];           // 0.75 KB
    __shared__ float vtl[GBN];              // 0.75 KB

    int f32 = probe_f32(shape_p);
    int tid = threadIdx.x;
    int wave = tid >> 6, lane = tid & 63;
    int fr = lane & 15, quad = lane >> 4;
    int mg = wave >> 2, wn = wave & 3;      // 2M x 4N wave grid

    // swizzle: panel P's 16 m-blocks all map to XCD P%8 (round-robin assumption)
    int lin = blockIdx.x;
    int xcd = lin & 7, slot = lin >> 3;
    int P = (slot >> 4) * 8 + xcd;
    int mblk = slot & 15;
    if (P >= GNP) return;
    int m0 = mblk * GBM;
    int v0 = P * 64;

    // cooperative staging (consumed after the epilogue barriers)
    for (int i = tid; i < GBM*60/4; i += 512)
        ((float4v*)Al)[i] = ((const float4v*)(Amat + (long)m0*60))[i];
    if (tid < 320) {
        int v = v0 + tid / 5;
        wl[tid] = (v < NV) ? ldf(weights, v*5 + tid % 5, f32) : 0.f;
    }
    if (tid < GBM*3)
        tl[tid] = ldf(transl, (long)m0*3 + tid, f32);
    if (tid >= 320) {
        int i = tid - 320;                  // 0..191
        vtl[i] = ((long)v0*3 + i < N3) ? ldf(v_template, (long)v0*3 + i, f32) : 0.f;
    }

    // per-wave staging runs: wave w owns runs 2w, 2w+1 of 16 x 1KB.
    int r0 = wave*2, r1 = wave*2 + 1;
    long aoff0 = 0, aoff1 = 0;              // frag offsets (without s term)
    const __hip_bfloat16* base0;
    const __hip_bfloat16* base1;
    int sstr0, sstr1;                       // per-step frag stride
    {
        if (r0 < 4) { base0 = Act; sstr0 = RB_A; aoff0 = mblk*4 + r0; }
        else {
            long rb = (long)P*12 + (r0 - 4);
            if (rb > RB_B-1) rb = RB_B-1;
            base0 = Wb; sstr0 = RB_B; aoff0 = rb;
        }
        if (r1 < 4) { base1 = Act; sstr1 = RB_A; aoff1 = mblk*4 + r1; }
        else {
            long rb = (long)P*12 + (r1 - 4);
            if (rb > RB_B-1) rb = RB_B-1;
            base1 = Wb; sstr1 = RB_B; aoff1 = rb;
        }
    }
    __hip_bfloat16* lds0[2] = { &stage[0][r0*FRAG], &stage[1][r0*FRAG] };
    __hip_bfloat16* lds1[2] = { &stage[0][r1*FRAG], &stage[1][r1*FRAG] };

    floatx4 acc[2][3];
#pragma unroll
    for (int q = 0; q < 2; ++q)
#pragma unroll
        for (int t = 0; t < 3; ++t) acc[q][t] = (floatx4){0.f,0.f,0.f,0.f};

    // drain prologue loads so DMA vmcnt counting is deterministic
    asm volatile("s_waitcnt vmcnt(0)" ::: "memory");
    __builtin_amdgcn_sched_barrier(0);
    // prologue: stage steps 0 and 1 (2 DMA issues per wave per step)
    GLDS16(base0 + ((long)0*sstr0 + aoff0)*FRAG + lane*8, lds0[0]);
    GLDS16(base1 + ((long)0*sstr1 + aoff1)*FRAG + lane*8, lds1[0]);
    GLDS16(base0 + ((long)1*sstr0 + aoff0)*FRAG + lane*8, lds0[1]);
    GLDS16(base1 + ((long)1*sstr1 + aoff1)*FRAG + lane*8, lds1[1]);

#pragma unroll
    for (int s = 0; s < NSTEP; ++s) {
        const int cb = s & 1;
        if (s == NSTEP-1) { asm volatile("s_waitcnt vmcnt(0)" ::: "memory"); }
        else              { asm volatile("s_waitcnt vmcnt(2)" ::: "memory"); }
        __builtin_amdgcn_sched_barrier(0);
        __builtin_amdgcn_s_barrier();       // all waves' stage(s) landed
        __builtin_amdgcn_sched_barrier(0);
        const __hip_bfloat16* sb = stage[cb];
        short8 a0 = *(const short8*)&sb[(mg*2 + 0)*FRAG + lane*8];
        short8 a1 = *(const short8*)&sb[(mg*2 + 1)*FRAG + lane*8];
        short8 b0 = *(const short8*)&sb[(4 + wn*3 + 0)*FRAG + lane*8];
        short8 b1 = *(const short8*)&sb[(4 + wn*3 + 1)*FRAG + lane*8];
        short8 b2 = *(const short8*)&sb[(4 + wn*3 + 2)*FRAG + lane*8];
        acc[0][0] = __builtin_amdgcn_mfma_f32_16x16x32_bf16(a0, b0, acc[0][0], 0, 0, 0);
        acc[0][1] = __builtin_amdgcn_mfma_f32_16x16x32_bf16(a0, b1, acc[0][1], 0, 0, 0);
        acc[0][2] = __builtin_amdgcn_mfma_f32_16x16x32_bf16(a0, b2, acc[0][2], 0, 0, 0);
        acc[1][0] = __builtin_amdgcn_mfma_f32_16x16x32_bf16(a1, b0, acc[1][0], 0, 0, 0);
        acc[1][1] = __builtin_amdgcn_mfma_f32_16x16x32_bf16(a1, b1, acc[1][1], 0, 0, 0);
        acc[1][2] = __builtin_amdgcn_mfma_f32_16x16x32_bf16(a1, b2, acc[1][2], 0, 0, 0);
        __builtin_amdgcn_sched_barrier(0);
        __builtin_amdgcn_s_barrier();       // all waves done reading buf cb
        __builtin_amdgcn_sched_barrier(0);
        if (s + 2 < NSTEP) {                // refill buf cb with step s+2
            GLDS16(base0 + ((long)(s+2)*sstr0 + aoff0)*FRAG + lane*8, lds0[cb]);
            GLDS16(base1 + ((long)(s+2)*sstr1 + aoff1)*FRAG + lane*8, lds1[cb]);
        }
    }

    // epilogue: 2 chunks of 16 m-rows per wave; per-wave LDS buffer
    __syncthreads();                        // full sync before LDS reuse pattern
    float* ch = chunk[wave];
    int mloc = lane >> 2, vq = lane & 3;    // 16 m x 4 vert-groups per chunk
#pragma unroll
    for (int q = 0; q < 2; ++q) {
#pragma unroll
        for (int t = 0; t < 3; ++t)
#pragma unroll
            for (int rr = 0; rr < 4; ++rr)
                ch[(quad*4 + rr)*CH_S + t*16 + fr] = acc[q][t][rr];
        __syncthreads();
        int mb = mg*32 + q*16 + mloc;       // block-local m
        long mglob = m0 + mb;
        const float* A = &Al[mb*60];
        float t0c = tl[mb*3+0], t1c = tl[mb*3+1], t2c = tl[mb*3+2];
        long obase = (mglob*NV + v0)*3;
#pragma unroll
        for (int vi = 0; vi < 4; ++vi) {
            int vloc = wn*16 + vq*4 + vi;   // block-local vertex 0..63
            int v = v0 + vloc;
            if (v < NV) {
                int o = mloc*CH_S + (vq*4 + vi)*3;
                float p0 = ch[o+0] + vtl[vloc*3 + 0];
                float p1 = ch[o+1] + vtl[vloc*3 + 1];
                float p2 = ch[o+2] + vtl[vloc*3 + 2];
                float w0 = wl[vloc*5+0], w1 = wl[vloc*5+1], w2 = wl[vloc*5+2];
                float w3 = wl[vloc*5+3], w4 = wl[vloc*5+4];
#pragma unroll
                for (int c = 0; c < 3; ++c) {
                    float t0 = w0*A[c*4+0] + w1*A[12+c*4+0] + w2*A[24+c*4+0] + w3*A[36+c*4+0] + w4*A[48+c*4+0];
                    float t1 = w0*A[c*4+1] + w1*A[12+c*4+1] + w2*A[24+c*4+1] + w3*A[36+c*4+1] + w4*A[48+c*4+1];
                    float t2 = w0*A[c*4+2] + w1*A[12+c*4+2] + w2*A[24+c*4+2] + w3*A[36+c*4+2] + w4*A[48+c*4+2];
                    float t3 = w0*A[c*4+3] + w1*A[12+c*4+3] + w2*A[24+c*4+3] + w3*A[36+c*4+3] + w4*A[48+c*4+3];
                    float tlc = (c == 0) ? t0c : ((c == 1) ? t1c : t2c);
                    float val = t0*p0 + t1*p1 + t2*p2 + t3 + tlc;
                    stf(out, obase + vloc*3 + c, val, f32);
                }
            }
        }
        __syncthreads();                    // chunk buffer reused next q
    }
}

// Fallback (small ws): register-direct from raw inputs; Act is step-major frag-linear.
__global__ __launch_bounds__(256) void k_gemm_lbs_small(
        const __hip_bfloat16* __restrict__ Act,
        const void* __restrict__ shapedirs,
        const void* __restrict__ posedirs,
        const void* __restrict__ v_template,
        const float* __restrict__ Amat,
        const void* __restrict__ weights,
        const void* __restrict__ transl,
        const int* __restrict__ flags,
        void* __restrict__ out) {
    __shared__ float tileS[4][16*49 + 4];
    __shared__ float AlS[4][960];
    __shared__ float wl[80];
    __shared__ __align__(16) __hip_bfloat16 Bs2[BN * 64];

    int f32 = flags[0];
    int tid = threadIdx.x;
    int wave = tid >> 6, lane = tid & 63;
    int fr = lane & 15, quad = lane >> 4;
    int m0 = blockIdx.x * 256;
    int n0 = blockIdx.y * BN;
    int v0 = blockIdx.y * 16;

    if (tid < 80) {
        int v = v0 + tid / 5;
        wl[tid] = (v < NV) ? ldf(weights, v*5 + tid % 5, f32) : 0.f;
    }
    for (int i = tid; i < BN * 64; i += 256) {
        int n = i >> 6, kk = i & 63;
        int nc = min(n0 + n, N3 - 1);
        float val = 0.f;
        if (kk < 16)      val = ldf(shapedirs, (long)nc*KBETA + 384 + kk, f32);
        else if (kk < 52) val = ldf(posedirs, (long)(kk-16)*N3 + nc, f32);
        Bs2[n*64 + kk] = __float2bfloat16(val);
    }
    __syncthreads();

    int Ra0 = (m0 >> 4) + wave*4;
    int nr[3];
#pragma unroll
    for (int t = 0; t < 3; ++t) nr[t] = min(n0 + t*16 + fr, N3 - 1);

    floatx4 acc[4][3];
#pragma unroll
    for (int sub = 0; sub < 4; ++sub)
#pragma unroll
        for (int t = 0; t < 3; ++t) acc[sub][t] = (floatx4){0.f,0.f,0.f,0.f};

#pragma unroll
    for (int s = 0; s < 14; ++s) {
        short8 bb[3];
#pragma unroll
        for (int t = 0; t < 3; ++t) {
            if (s < 12) bb[t] = ld8bf(shapedirs, (long)nr[t]*KBETA + s*32 + quad*8, f32);
            else        bb[t] = *(short8*)&Bs2[(t*16 + fr)*64 + (s-12)*32 + quad*8];
        }
#pragma unroll
        for (int sub = 0; sub < 4; ++sub) {
            short8 a = *(const short8*)(Act + (((long)s*RB_A + Ra0 + sub)*64 + lane)*8);
#pragma unroll
            for (int t = 0; t < 3; ++t)
                acc[sub][t] = __builtin_amdgcn_mfma_f32_16x16x32_bf16(a, bb[t], acc[sub][t], 0, 0, 0);
        }
    }

    int vloc = fr, rgrp = quad;
    int v = v0 + vloc;
    float tpl0 = 0.f, tpl1 = 0.f, tpl2 = 0.f;
    if (v < NV) {
        tpl0 = ldf(v_template, v*3 + 0, f32);
        tpl1 = ldf(v_template, v*3 + 1, f32);
        tpl2 = ldf(v_template, v*3 + 2, f32);
    }
    float w0 = wl[vloc*5+0], w1 = wl[vloc*5+1], w2 = wl[vloc*5+2];
    float w3 = wl[vloc*5+3], w4 = wl[vloc*5+4];
    for (int sub = 0; sub < 4; ++sub) {
#pragma unroll
        for (int t = 0; t < 3; ++t)
#pragma unroll
            for (int rr = 0; rr < 4; ++rr)
                tileS[wave][(quad*4 + rr)*49 + t*16 + fr] = acc[sub][t][rr];
        for (int i = lane; i < 960; i += 64)
            AlS[wave][i] = Amat[(long)(m0 + wave*64 + sub*16)*60 + i];
        __syncthreads();
        if (v < NV) {
#pragma unroll
            for (int rr = 0; rr < 4; ++rr) {
                int mloc = rgrp*4 + rr;
                long m = m0 + wave*64 + sub*16 + mloc;
                float p0 = tileS[wave][mloc*49 + vloc*3 + 0] + tpl0;
                float p1 = tileS[wave][mloc*49 + vloc*3 + 1] + tpl1;
                float p2 = tileS[wave][mloc*49 + vloc*3 + 2] + tpl2;
                const float* A = &AlS[wave][mloc*60];
#pragma unroll
                for (int c = 0; c < 3; ++c) {
                    float t0 = w0*A[c*4+0] + w1*A[12+c*4+0] + w2*A[24+c*4+0] + w3*A[36+c*4+0] + w4*A[48+c*4+0];
                    float t1 = w0*A[c*4+1] + w1*A[12+c*4+1] + w2*A[24+c*4+1] + w3*A[36+c*4+1] + w4*A[48+c*4+1];
                    float t2 = w0*A[c*4+2] + w1*A[12+c*4+2] + w2*A[24+c*4+2] + w3*A[36+c*4+2] + w4*A[48+c*4+2];
                    float t3 = w0*A[c*4+3] + w1*A[12+c*4+3] + w2*A[24+c*4+3] + w3*A[36+c*4+3] + w4*A[48+c*4+3];
                    float val = t0*p0 + t1*p1 + t2*p2 + t3 + ldf(transl, m*3 + c, f32);
                    stf(out, (m*NV + v)*3 + c, val, f32);
                }
            }
        }
        __syncthreads();
    }
}

__global__ __launch_bounds__(64) void k_lmk(const void* __restrict__ verts,
                                            const void* __restrict__ bary,
                                            const int* __restrict__ faces,
                                            const void* __restrict__ lmk_idx,
                                            const void* __restrict__ transl,
                                            const float* __restrict__ reg,
                                            const void* __restrict__ shape_p,
                                            void* __restrict__ out) {
    int f32 = probe_f32(shape_p);
    int i64 = probe_i64(lmk_idx);
    int b = blockIdx.x, tid = threadIdx.x;
    if (b == 0 && tid == 63)
        stf(out, (long)BATCH*NV*3 + (long)BATCH*NLMK*3, reg[0], f32);
    if (tid >= NLMK) return;
    int f = i64 ? (int)((const long long*)lmk_idx)[tid]
                : ((const int*)lmk_idx)[tid];
    float acc[3] = {0.f, 0.f, 0.f};
    float bsum = 0.f;
    for (int fi = 0; fi < 3; ++fi) {
        int vi = faces[f*3 + fi];
        float bc = ldf(bary, tid*3 + fi, f32);
        bsum += bc;
#pragma unroll
        for (int c = 0; c < 3; ++c)
            acc[c] += bc * ldf(verts, ((long)b*NV + vi)*3 + c, f32);
    }
#pragma unroll
    for (int c = 0; c < 3; ++c) {
        float val = acc[c] + (1.f - bsum) * ldf(transl, b*3 + c, f32);
        stf(out, (long)BATCH*NV*3 + ((long)b*NLMK + tid)*3 + c, val, f32);
    }
}

extern "C" void kernel_launch(void* const* d_in, const int* in_sizes, int n_in,
                              void* d_out, int out_size, void* d_ws, size_t ws_size,
                              hipStream_t stream) {
    const void* shape_p   = d_in[0];
    const void* expr_p    = d_in[1];
    const void* grot      = d_in[2];
    const void* neck      = d_in[3];
    const void* jaw       = d_in[4];
    const void* eye       = d_in[5];
    const void* transl    = d_in[6];
    const void* v_templ   = d_in[7];
    const void* shapedirs = d_in[8];
    const void* posedirs  = d_in[9];
    const void* Jreg      = d_in[10];
    const void* weights   = d_in[11];
    const void* bary      = d_in[12];
    const int*  faces     = (const int*)d_in[14];
    const void* lmk_idx   = d_in[15];

    char* ws = (char*)d_ws;
    float* JS      = (float*)(ws + WS_JS);
    float* baseJ   = (float*)(ws + WS_BASEJ);
    float* reg     = (float*)(ws + WS_REG);
    int*   flags   = (int*)(ws + WS_FLAGS);
    float* Amat    = (float*)(ws + WS_AMAT);
    __hip_bfloat16* Act = (__hip_bfloat16*)(ws + WS_ACT);
    __hip_bfloat16* Wb  = (__hip_bfloat16*)(ws + WS_WB);
    float* PART    = (float*)d_out;   // scratch before verts are written
    bool big = ws_size >= (size_t)WS_FULL;

    if (big) {
        k_prep<<<PK_BETA_BLKS + PK_POSE_BLKS + PK_JS_BLKS, 256, 0, stream>>>(
            shapedirs, posedirs, Jreg, v_templ, shape_p, reg, Wb, PART);
        k_js_red<<<24, 256, 0, stream>>>(PART, JS, baseJ);
    } else {
        k_init<<<24, 256, 0, stream>>>((float*)ws, shape_p, lmk_idx, flags);
        k_js_atomic<<<dim3(3, 64), 256, 0, stream>>>(Jreg, shapedirs, v_templ, flags, JS, baseJ);
    }
    k_batch<<<BATCH, 64, 0, stream>>>(shape_p, expr_p, grot, neck, jaw, eye,
                                      JS, baseJ, Act, Amat, reg);
    if (big) {
        // swizzled 1D grid: 10 panel-groups * 8 xcd * 16 m = 1280 (16 no-ops)
        k_gemm_lbs_big<<<GGRID, 512, 0, stream>>>(Act, Wb, v_templ, Amat,
                                                  weights, transl, shape_p, d_out);
    } else {
        dim3 grid(BATCH/256, (N3 + BN - 1)/BN);
        k_gemm_lbs_small<<<grid, 256, 0, stream>>>(Act, shapedirs, posedirs, v_templ,
                                                   Amat, weights, transl, flags, d_out);
    }
    k_lmk<<<BATCH, 64, 0, stream>>>(d_out, bary, faces, lmk_idx, transl, reg, shape_p, d_out);
}

// Round 8
// 214.765 us; speedup vs baseline: 1.2722x; 1.1849x over previous
//
#include <hip/hip_runtime.h>
#include <hip/hip_bf16.h>

#define BATCH 1024
#define NV 5023
#define NJOINT 5
#define NLMK 51
#define N3 (NV*3)        // 15069
#define NPADB 15072      // N3 padded to multiple of 48 (and of 16)
#define KBETA 400
#define KTOT 448         // 400 betas + 36 pose_feature + 12 zero pad
#define NSTEP 14         // KTOT/32 MFMA k-steps
#define RB_B (NPADB/16)  // 942 row-blocks in Wb
#define RB_A 64          // 1024/16 row-blocks in Act
#define FRAG 512         // elems per (s,R) fragment: 64 lanes * 8 bf16

#define BM 64            // batches per block (small path)
#define BN 48            // output cols per block = 16 vertices (small path)

// k_prep regions
#define PK_BETA_CH (NPADB*50)        // 753600 16B-chunks, read-linear
#define PK_BETA_BLKS 2944            // ceil(753600/256)
#define PK_POSE_CH (RB_B*96)         // 90432 chunks
#define PK_POSE_BLKS 354             // ceil(90432/256)
#define NVC2 360                     // js v-chunks (14 verts each)
#define VCH 14
#define PK_JS_BLKS (3*NVC2)          // 1080

// big-path GEMM geometry: tile-split, no inter-wave reduction
#define GBM 64           // batches per block
#define GBN 192          // output cols per block = 64 vertices
#define GNP 79           // ceil(5023/64) panels
#define GGRID 1280       // ceil(79/8)*8 * 16 m-blocks
#define CH_S 52          // chunk stride (floats): 4*52 % 32 == 16 -> 2-way = free
#define CH_PAD 4         // per-chunk pad so sub-chunk bases de-alias banks

typedef __attribute__((ext_vector_type(8))) short short8;
typedef __attribute__((ext_vector_type(4))) float floatx4;
typedef __attribute__((ext_vector_type(4))) float float4v;

// async global->LDS DMA, 16B per lane
#define GLDS16(gp, lp) \
    __builtin_amdgcn_global_load_lds( \
        (const __attribute__((address_space(1))) void*)(gp), \
        (__attribute__((address_space(3))) void*)(lp), 16, 0, 0)

// ---------------- workspace byte offsets ----------------
#define WS_JS      0          // 6000 f32
#define WS_BASEJ   24064      // 15 f32
#define WS_REG     24512      // 1 f32
#define WS_FLAGS   24520      // 2 ints (fallback path only)
#define WS_AMAT    24576      // 1024*60 f32   -> ends 270336
#define WS_ACT     270336     // 1024*448 bf16 (step-major frag-linear) -> ends 1187840
#define WS_WB      1187840    // 15072*448 bf16 (step-major frag-linear) -> ends 14692352
#define WS_FULL    14692352

__device__ __forceinline__ float ldf(const void* p, long i, int f32) {
    if (f32) return ((const float*)p)[i];
    return __bfloat162float(((const __hip_bfloat16*)p)[i]);
}
__device__ __forceinline__ short8 ld8bf(const void* p, long i, int f32) {
    if (f32) {
        float4v a = *(const float4v*)((const float*)p + i);
        float4v b = *(const float4v*)((const float*)p + i + 4);
        short8 r;
#pragma unroll
        for (int j = 0; j < 4; ++j) {
            __hip_bfloat16 h = __float2bfloat16(a[j]);
            r[j] = *reinterpret_cast<short*>(&h);
        }
#pragma unroll
        for (int j = 0; j < 4; ++j) {
            __hip_bfloat16 h = __float2bfloat16(b[j]);
            r[4 + j] = *reinterpret_cast<short*>(&h);
        }
        return r;
    }
    return *(const short8*)((const __hip_bfloat16*)p + i);
}
__device__ __forceinline__ void stf(void* p, long i, float v, int f32) {
    if (f32) ((float*)p)[i] = v;
    else ((__hip_bfloat16*)p)[i] = __float2bfloat16(v);
}

// step-major fragment-linear Act index
__device__ __forceinline__ long act2_off(int b, int k) {
    return (((long)(k >> 5) * RB_A + (b >> 4)) * 64 + ((k >> 3) & 3) * 16 + (b & 15)) * 8 + (k & 7);
}

__device__ __forceinline__ int probe_f32(const void* shape_p) {
    int lane = threadIdx.x & 63;
    unsigned short h = ((const unsigned short*)shape_p)[2 * lane];
    union { unsigned short u; __hip_bfloat16 b; } cv; cv.u = h;
    float v = fabsf(__bfloat162float(cv.b));
    if (v != v) v = 3.4e38f;
#pragma unroll
    for (int off = 32; off; off >>= 1) v = fmaxf(v, __shfl_down(v, off));
    v = __shfl(v, 0);
    return v > 1e4f;
}
__device__ __forceinline__ int probe_i64(const void* lmk_idx) {
    int lane = threadIdx.x & 63;
    const int* q = (const int*)lmk_idx;
    int odd_nonzero = (lane < 25) && (q[2*lane + 1] != 0);
    unsigned long long b = __ballot(odd_nonzero);
    return b == 0ull;
}

// fallback-path init: zero JS/baseJ/reg + write flags
__global__ void k_init(float* ws0, const void* shape_p, const void* lmk_idx, int* flags) {
    int i = blockIdx.x * 256 + threadIdx.x;
    if (i < 6129) ws0[i] = 0.f;
    if (blockIdx.x == 0 && threadIdx.x < 64) {
        int f = probe_f32(shape_p);
        int i64 = probe_i64(lmk_idx);
        if (threadIdx.x == 0) { flags[0] = f; flags[1] = i64; }
    }
}

// Fused prep (big path), three concurrent regions (r7 structure) + JS zeroing
// by the first beta blocks (k_js_red runs as a LATER kernel -> ordering safe).
__global__ __launch_bounds__(256) void k_prep(const void* __restrict__ shapedirs,
                                              const void* __restrict__ posedirs,
                                              const void* __restrict__ Jreg,
                                              const void* __restrict__ v_template,
                                              const void* __restrict__ shape_p,
                                              float* __restrict__ reg,
                                              float* __restrict__ JS,
                                              float* __restrict__ baseJ,
                                              __hip_bfloat16* __restrict__ Wb,
                                              float* __restrict__ PART) {
    __shared__ float jl[NJOINT * VCH];
    int f32 = probe_f32(shape_p);
    int blk = blockIdx.x, tid = threadIdx.x;
    if (blk < PK_BETA_BLKS) {
        if (blk == 0 && tid == 0) reg[0] = 0.f;
        if (blk < 24) {                      // zero JS/baseJ for atomic js_red
            int zi = blk * 256 + tid;
            if (zi < 6000) JS[zi] = 0.f;
            if (zi < 15) baseJ[zi] = 0.f;
        }
        int g = blk * 256 + tid;
        if (g >= PK_BETA_CH) return;
        int n = g / 50, kg = g - n * 50;     // row n, k = kg*8 (contiguous read)
        short8 o;
#pragma unroll
        for (int e = 0; e < 8; ++e) o[e] = 0;
        if (n < N3) o = ld8bf(shapedirs, (long)n * KBETA + kg * 8, f32);
        long chunk = ((long)(kg >> 2) * RB_B + (n >> 4)) * 64 + (kg & 3) * 16 + (n & 15);
        *(short8*)(Wb + chunk * 8) = o;
    } else if (blk < PK_BETA_BLKS + PK_POSE_BLKS) {
        int g = (blk - PK_BETA_BLKS) * 256 + tid;
        if (g >= PK_POSE_CH) return;
        int R = g / 96, rem = g - R * 96;
        int c = rem >> 4, fr = rem & 15;
        int n = R * 16 + fr;
        int k0 = KBETA + 8 * c;
        short8 o;
#pragma unroll
        for (int e = 0; e < 8; ++e) o[e] = 0;
        if (n < N3) {
#pragma unroll
            for (int e = 0; e < 8; ++e) {
                int kk = k0 + e - KBETA;
                float val = (kk < 36) ? ldf(posedirs, (long)kk * N3 + n, f32) : 0.f;
                __hip_bfloat16 h = __float2bfloat16(val);
                o[e] = *reinterpret_cast<short*>(&h);
            }
        }
        long chunk = ((long)(k0 >> 5) * RB_B + R) * 64 + ((k0 >> 3) & 3) * 16 + fr;
        *(short8*)(Wb + chunk * 8) = o;
    } else {
        int b2 = blk - (PK_BETA_BLKS + PK_POSE_BLKS);  // 0..1079
        int k = b2 / NVC2;                    // 0..2
        int vc = b2 - k * NVC2;               // 0..359
        int v0 = vc * VCH;
        if (tid < NJOINT * VCH) {
            int j = tid / VCH, i = tid - j * VCH;
            int v = min(v0 + i, NV - 1);
            jl[tid] = ldf(Jreg, (long)j * NV + v, f32);
        }
        __syncthreads();
        int l2 = tid + 256;                   // 400 == template col
        float acc1[NJOINT] = {0,0,0,0,0};
        float acc2[NJOINT] = {0,0,0,0,0};
#pragma unroll
        for (int i = 0; i < VCH; ++i) {
            int v = v0 + i;
            if (v >= NV) break;
            float s1 = ldf(shapedirs, (long)v*1200 + k*400 + tid, f32);
            float s2 = 0.f;
            if (l2 < 400)       s2 = ldf(shapedirs, (long)v*1200 + k*400 + l2, f32);
            else if (l2 == 400) s2 = ldf(v_template, v*3 + k, f32);
#pragma unroll
            for (int j = 0; j < NJOINT; ++j) {
                float jr = jl[j*VCH + i];
                acc1[j] += jr * s1;
                acc2[j] += jr * s2;
            }
        }
        long base = ((long)(k*NVC2 + vc)*5)*401;
#pragma unroll
        for (int j = 0; j < NJOINT; ++j) {
            PART[base + j*401 + tid] = acc1[j];
            if (l2 <= 400) PART[base + j*401 + l2] = acc2[j];
        }
    }
}

// Reduce over NVC2 chunks -> JS / baseJ. 6-way k-split + atomicAdd
// (JS/baseJ zeroed by k_prep, which completes before this kernel starts).
__global__ __launch_bounds__(256) void k_js_red(const float* __restrict__ PART,
                                                float* __restrict__ JS,
                                                float* __restrict__ baseJ) {
    int o = blockIdx.x * 256 + threadIdx.x;
    if (o >= 3*5*401) return;
    int g = blockIdx.y;                  // 0..5, 60 chunks each
    int k = o / 2005, r = o - k*2005;
    int j = r / 401, l = r - j*401;
    float s = 0.f;
    long base = ((long)(k*NVC2 + g*60)*5 + j)*401 + l;
    for (int vc = 0; vc < 60; ++vc) s += PART[base + (long)vc*2005];
    if (l < 400) atomicAdd(&JS[j*1200 + k*400 + l], s);
    else         atomicAdd(&baseJ[j*3 + k], s);
}

// Fallback JS (atomic, raw shapedirs) for small ws.
__global__ void k_js_atomic(const void* __restrict__ Jreg,
                            const void* __restrict__ shapedirs,
                            const void* __restrict__ v_template,
                            const int* __restrict__ flags,
                            float* __restrict__ JS, float* __restrict__ baseJ) {
    int f32 = flags[0];
    int k = blockIdx.x, vc = blockIdx.y, tid = threadIdx.x;
    int v0 = vc * 79, v1 = min(NV, v0 + 79);
    int l2 = tid + 256;
    float acc1[NJOINT] = {0,0,0,0,0};
    float acc2[NJOINT] = {0,0,0,0,0};
    for (int v = v0; v < v1; ++v) {
        float s1 = ldf(shapedirs, (long)v*1200 + k*400 + tid, f32);
        float s2 = 0.f;
        if (l2 < 400)       s2 = ldf(shapedirs, (long)v*1200 + k*400 + l2, f32);
        else if (l2 == 400) s2 = ldf(v_template, v*3 + k, f32);
#pragma unroll
        for (int j = 0; j < NJOINT; ++j) {
            float jr = ldf(Jreg, j*NV + v, f32);
            acc1[j] += jr * s1;
            acc2[j] += jr * s2;
        }
    }
#pragma unroll
    for (int j = 0; j < NJOINT; ++j) {
        atomicAdd(&JS[j*1200 + k*400 + tid], acc1[j]);
        if (l2 < 400)       atomicAdd(&JS[j*1200 + k*400 + l2], acc2[j]);
        else if (l2 == 400) atomicAdd(&baseJ[j*3 + k], acc2[j]);
    }
}

// Per-batch: betas->Act(bf16, step-major frag-linear), joints, rodrigues, chain, A, reg
__global__ __launch_bounds__(64) void k_batch(
        const void* __restrict__ shape_p, const void* __restrict__ expr_p,
        const void* __restrict__ grot, const void* __restrict__ neck,
        const void* __restrict__ jaw,  const void* __restrict__ eye,
        const float* __restrict__ JS, const float* __restrict__ baseJ,
        __hip_bfloat16* __restrict__ Act, float* __restrict__ Amat, float* __restrict__ reg) {
    int f32 = probe_f32(shape_p);
    int b = blockIdx.x, tid = threadIdx.x;
    __shared__ float betas[400];
    __shared__ float Rm[NJOINT][9];
    __shared__ float joints[NJOINT][3];
    __shared__ float Gm[NJOINT][12];

    for (int i = tid; i < 400; i += 64) {
        float v = (i < 300) ? ldf(shape_p, b*300 + i, f32)
                            : ldf(expr_p, b*100 + i - 300, f32);
        betas[i] = v;
        Act[act2_off(b, i)] = __float2bfloat16(v);
    }
    if (tid >= 36 && tid < 48) Act[act2_off(b, 400 + tid)] = __float2bfloat16(0.f);
    __syncthreads();

    if (tid < 60) {
        int o = tid % 15, q = tid / 15;
        int j = o / 3, kk = o - 3*j;
        const float* js = &JS[j*1200 + kk*400 + q*100];
        float s = 0.f;
        for (int l = 0; l < 100; ++l) s += js[l] * betas[q*100 + l];
        s += __shfl_down(s, 15);
        s += __shfl_down(s, 30);
        if (q == 0) joints[j][kk] = s + baseJ[o];
    }
    if (tid < NJOINT) {
        int j = tid;
        float r[3];
        for (int c = 0; c < 3; ++c) {
            if (j == 0)      r[c] = ldf(grot, b*3 + c, f32);
            else if (j == 1) r[c] = ldf(neck, b*3 + c, f32);
            else if (j == 2) r[c] = ldf(jaw,  b*3 + c, f32);
            else if (j == 3) r[c] = ldf(eye,  b*6 + c, f32);
            else             r[c] = ldf(eye,  b*6 + 3 + c, f32);
        }
        float a0 = r[0] + 1e-8f, a1 = r[1] + 1e-8f, a2 = r[2] + 1e-8f;
        float angle = sqrtf(a0*a0 + a1*a1 + a2*a2);
        float inv = 1.0f / angle;
        float rx = r[0]*inv, ry = r[1]*inv, rz = r[2]*inv;
        float s = sinf(angle), c = cosf(angle);
        float K[9] = {0.f, -rz, ry,  rz, 0.f, -rx,  -ry, rx, 0.f};
        float K2[9];
        for (int rr = 0; rr < 3; ++rr)
            for (int cc = 0; cc < 3; ++cc) {
                float t = 0.f;
                for (int m = 0; m < 3; ++m) t += K[rr*3+m] * K[m*3+cc];
                K2[rr*3+cc] = t;
            }
        for (int i2 = 0; i2 < 9; ++i2) {
            float id = (i2 == 0 || i2 == 4 || i2 == 8) ? 1.f : 0.f;
            Rm[j][i2] = id + s*K[i2] + (1.f - c)*K2[i2];
        }
    }
    __syncthreads();

    if (tid < 36) {
        int i = tid / 9 + 1, rc = tid - (tid/9)*9;
        float id = (rc == 0 || rc == 4 || rc == 8) ? 1.f : 0.f;
        Act[act2_off(b, 400 + tid)] = __float2bfloat16(Rm[i][rc] - id);
    }
    if (tid == 0) {
        for (int rr = 0; rr < 3; ++rr) {
            for (int cc = 0; cc < 3; ++cc) Gm[0][rr*4+cc] = Rm[0][rr*3+cc];
            Gm[0][rr*4+3] = joints[0][rr];
        }
        const int par[NJOINT] = {-1, 0, 1, 1, 1};
        for (int j = 1; j < NJOINT; ++j) {
            int p = par[j];
            float rel[3];
            for (int c2 = 0; c2 < 3; ++c2) rel[c2] = joints[j][c2] - joints[p][c2];
            for (int rr = 0; rr < 3; ++rr) {
                for (int cc = 0; cc < 3; ++cc) {
                    float t = 0.f;
                    for (int m = 0; m < 3; ++m) t += Gm[p][rr*4+m] * Rm[j][m*3+cc];
                    Gm[j][rr*4+cc] = t;
                }
                float t = Gm[p][rr*4+3];
                for (int m = 0; m < 3; ++m) t += Gm[p][rr*4+m] * rel[m];
                Gm[j][rr*4+3] = t;
            }
        }
    }
    __syncthreads();

    if (tid < 60) {
        int j = tid / 12, e = tid - j*12, rr = e / 4, cc = e - rr*4;
        float val = Gm[j][e];
        if (cc == 3)
            for (int m = 0; m < 3; ++m) val -= Gm[j][rr*4+m] * joints[j][m];
        Amat[b*60 + tid] = val;
    }

    float part = 0.f;
    for (int i = tid; i < 400; i += 64) part += betas[i]*betas[i];
    part *= 0.001f;
    if (tid == 0) {
        float nn = 0.f, jj = 0.f;
        for (int c = 0; c < 3; ++c) {
            float nv = ldf(neck, b*3+c, f32);
            float jv = ldf(jaw,  b*3+c, f32);
            nn += nv*nv; jj += jv*jv;
        }
        part += 100.f*nn + 0.001f*jj;
    }
    for (int off = 32; off; off >>= 1) part += __shfl_down(part, off);
    if (tid == 0) atomicAdd(reg, part);
}

// Fused GEMM + LBS. K-loop UNCHANGED (r6/r7 DMA pipeline, control).
// NEW epilogue v2: the old per-thread scalar stores were fully divergent
// (64 lanes spanning 16 rows x 60KB -> ~64 transactions/instruction;
// ~12k store-instrs/block = the invariant ~25-40us wall across r4-r7).
// Now: acc -> chunk (as before) -> cooperative LBS into a 32x192 f32
// LDS vbuf (aliasing the dead `stage` buffer) -> coalesced store phase
// with consecutive-lane -> consecutive-address mapping.
__global__ __launch_bounds__(512, 2) void k_gemm_lbs_big(
        const __hip_bfloat16* __restrict__ Act,
        const __hip_bfloat16* __restrict__ Wb,
        const void* __restrict__ v_template,
        const float* __restrict__ Amat,
        const void* __restrict__ weights,
        const void* __restrict__ transl,
        const void* __restrict__ shape_p,
        void* __restrict__ out) {
    __shared__ __align__(16) __hip_bfloat16 stage[2][16 * FRAG];  // 32 KB
    __shared__ float chunk[8][16 * CH_S + CH_PAD];  // 26.8 KB
    __shared__ float Al[GBM * 60];          // 15.4 KB
    __shared__ float wl[64 * 5];            // 1.25 KB
    __shared__ float tl[GBM * 3];           // 0.75 KB
    __shared__ float vtl[GBN];              // 0.75 KB

    int f32 = probe_f32(shape_p);
    int tid = threadIdx.x;
    int wave = tid >> 6, lane = tid & 63;
    int fr = lane & 15, quad = lane >> 4;
    int mg = wave >> 2, wn = wave & 3;      // 2M x 4N wave grid

    int lin = blockIdx.x;
    int xcd = lin & 7, slot = lin >> 3;
    int P = (slot >> 4) * 8 + xcd;
    int mblk = slot & 15;
    if (P >= GNP) return;
    int m0 = mblk * GBM;
    int v0 = P * 64;

    // cooperative staging (consumed after the epilogue barriers)
    for (int i = tid; i < GBM*60/4; i += 512)
        ((float4v*)Al)[i] = ((const float4v*)(Amat + (long)m0*60))[i];
    if (tid < 320) {
        int v = v0 + tid / 5;
        wl[tid] = (v < NV) ? ldf(weights, v*5 + tid % 5, f32) : 0.f;
    }
    if (tid < GBM*3)
        tl[tid] = ldf(transl, (long)m0*3 + tid, f32);
    if (tid >= 320) {
        int i = tid - 320;                  // 0..191
        vtl[i] = ((long)v0*3 + i < N3) ? ldf(v_template, (long)v0*3 + i, f32) : 0.f;
    }

    // per-wave staging runs: wave w owns runs 2w, 2w+1 of 16 x 1KB.
    int r0 = wave*2, r1 = wave*2 + 1;
    long aoff0 = 0, aoff1 = 0;
    const __hip_bfloat16* base0;
    const __hip_bfloat16* base1;
    int sstr0, sstr1;
    {
        if (r0 < 4) { base0 = Act; sstr0 = RB_A; aoff0 = mblk*4 + r0; }
        else {
            long rb = (long)P*12 + (r0 - 4);
            if (rb > RB_B-1) rb = RB_B-1;
            base0 = Wb; sstr0 = RB_B; aoff0 = rb;
        }
        if (r1 < 4) { base1 = Act; sstr1 = RB_A; aoff1 = mblk*4 + r1; }
        else {
            long rb = (long)P*12 + (r1 - 4);
            if (rb > RB_B-1) rb = RB_B-1;
            base1 = Wb; sstr1 = RB_B; aoff1 = rb;
        }
    }
    __hip_bfloat16* lds0[2] = { &stage[0][r0*FRAG], &stage[1][r0*FRAG] };
    __hip_bfloat16* lds1[2] = { &stage[0][r1*FRAG], &stage[1][r1*FRAG] };

    floatx4 acc[2][3];
#pragma unroll
    for (int q = 0; q < 2; ++q)
#pragma unroll
        for (int t = 0; t < 3; ++t) acc[q][t] = (floatx4){0.f,0.f,0.f,0.f};

    asm volatile("s_waitcnt vmcnt(0)" ::: "memory");
    __builtin_amdgcn_sched_barrier(0);
    GLDS16(base0 + ((long)0*sstr0 + aoff0)*FRAG + lane*8, lds0[0]);
    GLDS16(base1 + ((long)0*sstr1 + aoff1)*FRAG + lane*8, lds1[0]);
    GLDS16(base0 + ((long)1*sstr0 + aoff0)*FRAG + lane*8, lds0[1]);
    GLDS16(base1 + ((long)1*sstr1 + aoff1)*FRAG + lane*8, lds1[1]);

#pragma unroll
    for (int s = 0; s < NSTEP; ++s) {
        const int cb = s & 1;
        if (s == NSTEP-1) { asm volatile("s_waitcnt vmcnt(0)" ::: "memory"); }
        else              { asm volatile("s_waitcnt vmcnt(2)" ::: "memory"); }
        __builtin_amdgcn_sched_barrier(0);
        __builtin_amdgcn_s_barrier();
        __builtin_amdgcn_sched_barrier(0);
        const __hip_bfloat16* sb = stage[cb];
        short8 a0 = *(const short8*)&sb[(mg*2 + 0)*FRAG + lane*8];
        short8 a1 = *(const short8*)&sb[(mg*2 + 1)*FRAG + lane*8];
        short8 b0 = *(const short8*)&sb[(4 + wn*3 + 0)*FRAG + lane*8];
        short8 b1 = *(const short8*)&sb[(4 + wn*3 + 1)*FRAG + lane*8];
        short8 b2 = *(const short8*)&sb[(4 + wn*3 + 2)*FRAG + lane*8];
        acc[0][0] = __builtin_amdgcn_mfma_f32_16x16x32_bf16(a0, b0, acc[0][0], 0, 0, 0);
        acc[0][1] = __builtin_amdgcn_mfma_f32_16x16x32_bf16(a0, b1, acc[0][1], 0, 0, 0);
        acc[0][2] = __builtin_amdgcn_mfma_f32_16x16x32_bf16(a0, b2, acc[0][2], 0, 0, 0);
        acc[1][0] = __builtin_amdgcn_mfma_f32_16x16x32_bf16(a1, b0, acc[1][0], 0, 0, 0);
        acc[1][1] = __builtin_amdgcn_mfma_f32_16x16x32_bf16(a1, b1, acc[1][1], 0, 0, 0);
        acc[1][2] = __builtin_amdgcn_mfma_f32_16x16x32_bf16(a1, b2, acc[1][2], 0, 0, 0);
        __builtin_amdgcn_sched_barrier(0);
        __builtin_amdgcn_s_barrier();
        __builtin_amdgcn_sched_barrier(0);
        if (s + 2 < NSTEP) {
            GLDS16(base0 + ((long)(s+2)*sstr0 + aoff0)*FRAG + lane*8, lds0[cb]);
            GLDS16(base1 + ((long)(s+2)*sstr1 + aoff1)*FRAG + lane*8, lds1[cb]);
        }
    }

    // ---- epilogue v2: LBS in LDS + coalesced stores ----
    __syncthreads();                        // stage is dead -> reuse as vbuf
    float* vbuf = (float*)stage;            // 32 rows x 192 f32 = 24.6 KB
    float* ch = chunk[wave];
    int mloc_w = lane;                      // vert for LBS phase
    float w0 = wl[mloc_w*5+0], w1 = wl[mloc_w*5+1], w2 = wl[mloc_w*5+2];
    float w3 = wl[mloc_w*5+3], w4 = wl[mloc_w*5+4];
    float vt0 = vtl[mloc_w*3+0], vt1 = vtl[mloc_w*3+1], vt2 = vtl[mloc_w*3+2];
    int coff = (mloc_w & 15) * 3;
    int wnl = mloc_w >> 4;
#pragma unroll
    for (int q = 0; q < 2; ++q) {
        // 1) acc -> per-wave chunk (transpose), as before
#pragma unroll
        for (int t = 0; t < 3; ++t)
#pragma unroll
            for (int rr = 0; rr < 4; ++rr)
                ch[(quad*4 + rr)*CH_S + t*16 + fr] = acc[q][t][rr];
        __syncthreads();
        // 2) LBS: thread = (row r32 = it*8+wave, vert = lane) -> vbuf
        int v = v0 + mloc_w;
#pragma unroll
        for (int it = 0; it < 4; ++it) {
            int r32 = it*8 + wave;          // uniform per wave
            int mb = ((r32 & 16) << 1) + q*16 + (r32 & 15);
            const float* A = &Al[mb*60];
            const float* cc2 = &chunk[((r32 >> 4) << 2) + wnl][(r32 & 15)*CH_S + coff];
            if (v < NV) {
                float p0 = cc2[0] + vt0;
                float p1 = cc2[1] + vt1;
                float p2 = cc2[2] + vt2;
                float* vb = &vbuf[r32*192 + mloc_w*3];
#pragma unroll
                for (int c = 0; c < 3; ++c) {
                    float t0 = w0*A[c*4+0] + w1*A[12+c*4+0] + w2*A[24+c*4+0] + w3*A[36+c*4+0] + w4*A[48+c*4+0];
                    float t1 = w0*A[c*4+1] + w1*A[12+c*4+1] + w2*A[24+c*4+1] + w3*A[36+c*4+1] + w4*A[48+c*4+1];
                    float t2 = w0*A[c*4+2] + w1*A[12+c*4+2] + w2*A[24+c*4+2] + w3*A[36+c*4+2] + w4*A[48+c*4+2];
                    float t3 = w0*A[c*4+3] + w1*A[12+c*4+3] + w2*A[24+c*4+3] + w3*A[36+c*4+3] + w4*A[48+c*4+3];
                    vb[c] = t0*p0 + t1*p1 + t2*p2 + t3 + tl[mb*3+c];
                }
            }
        }
        __syncthreads();
        // 3) coalesced store: 6144 floats, consecutive tid -> consecutive addr
#pragma unroll
        for (int it = 0; it < 12; ++it) {
            int idx = it*512 + tid;
            int r32 = idx / 192;
            int col = idx - r32*192;
            if (v0*3 + col < N3) {
                int mb = ((r32 & 16) << 1) + q*16 + (r32 & 15);
                stf(out, ((long)(m0 + mb)*NV + v0)*3 + col, vbuf[idx], f32);
            }
        }
        __syncthreads();                    // chunk & vbuf reused next q
    }
}

// Fallback (small ws): register-direct from raw inputs; Act is step-major frag-linear.
__global__ __launch_bounds__(256) void k_gemm_lbs_small(
        const __hip_bfloat16* __restrict__ Act,
        const void* __restrict__ shapedirs,
        const void* __restrict__ posedirs,
        const void* __restrict__ v_template,
        const float* __restrict__ Amat,
        const void* __restrict__ weights,
        const void* __restrict__ transl,
        const int* __restrict__ flags,
        void* __restrict__ out) {
    __shared__ float tileS[4][16*49 + 4];
    __shared__ float AlS[4][960];
    __shared__ float wl[80];
    __shared__ __align__(16) __hip_bfloat16 Bs2[BN * 64];

    int f32 = flags[0];
    int tid = threadIdx.x;
    int wave = tid >> 6, lane = tid & 63;
    int fr = lane & 15, quad = lane >> 4;
    int m0 = blockIdx.x * 256;
    int n0 = blockIdx.y * BN;
    int v0 = blockIdx.y * 16;

    if (tid < 80) {
        int v = v0 + tid / 5;
        wl[tid] = (v < NV) ? ldf(weights, v*5 + tid % 5, f32) : 0.f;
    }
    for (int i = tid; i < BN * 64; i += 256) {
        int n = i >> 6, kk = i & 63;
        int nc = min(n0 + n, N3 - 1);
        float val = 0.f;
        if (kk < 16)      val = ldf(shapedirs, (long)nc*KBETA + 384 + kk, f32);
        else if (kk < 52) val = ldf(posedirs, (long)(kk-16)*N3 + nc, f32);
        Bs2[n*64 + kk] = __float2bfloat16(val);
    }
    __syncthreads();

    int Ra0 = (m0 >> 4) + wave*4;
    int nr[3];
#pragma unroll
    for (int t = 0; t < 3; ++t) nr[t] = min(n0 + t*16 + fr, N3 - 1);

    floatx4 acc[4][3];
#pragma unroll
    for (int sub = 0; sub < 4; ++sub)
#pragma unroll
        for (int t = 0; t < 3; ++t) acc[sub][t] = (floatx4){0.f,0.f,0.f,0.f};

#pragma unroll
    for (int s = 0; s < 14; ++s) {
        short8 bb[3];
#pragma unroll
        for (int t = 0; t < 3; ++t) {
            if (s < 12) bb[t] = ld8bf(shapedirs, (long)nr[t]*KBETA + s*32 + quad*8, f32);
            else        bb[t] = *(short8*)&Bs2[(t*16 + fr)*64 + (s-12)*32 + quad*8];
        }
#pragma unroll
        for (int sub = 0; sub < 4; ++sub) {
            short8 a = *(const short8*)(Act + (((long)s*RB_A + Ra0 + sub)*64 + lane)*8);
#pragma unroll
            for (int t = 0; t < 3; ++t)
                acc[sub][t] = __builtin_amdgcn_mfma_f32_16x16x32_bf16(a, bb[t], acc[sub][t], 0, 0, 0);
        }
    }

    int vloc = fr, rgrp = quad;
    int v = v0 + vloc;
    float tpl0 = 0.f, tpl1 = 0.f, tpl2 = 0.f;
    if (v < NV) {
        tpl0 = ldf(v_template, v*3 + 0, f32);
        tpl1 = ldf(v_template, v*3 + 1, f32);
        tpl2 = ldf(v_template, v*3 + 2, f32);
    }
    float w0 = wl[vloc*5+0], w1 = wl[vloc*5+1], w2 = wl[vloc*5+2];
    float w3 = wl[vloc*5+3], w4 = wl[vloc*5+4];
    for (int sub = 0; sub < 4; ++sub) {
#pragma unroll
        for (int t = 0; t < 3; ++t)
#pragma unroll
            for (int rr = 0; rr < 4; ++rr)
                tileS[wave][(quad*4 + rr)*49 + t*16 + fr] = acc[sub][t][rr];
        for (int i = lane; i < 960; i += 64)
            AlS[wave][i] = Amat[(long)(m0 + wave*64 + sub*16)*60 + i];
        __syncthreads();
        if (v < NV) {
#pragma unroll
            for (int rr = 0; rr < 4; ++rr) {
                int mloc = rgrp*4 + rr;
                long m = m0 + wave*64 + sub*16 + mloc;
                float p0 = tileS[wave][mloc*49 + vloc*3 + 0] + tpl0;
                float p1 = tileS[wave][mloc*49 + vloc*3 + 1] + tpl1;
                float p2 = tileS[wave][mloc*49 + vloc*3 + 2] + tpl2;
                const float* A = &AlS[wave][mloc*60];
#pragma unroll
                for (int c = 0; c < 3; ++c) {
                    float t0 = w0*A[c*4+0] + w1*A[12+c*4+0] + w2*A[24+c*4+0] + w3*A[36+c*4+0] + w4*A[48+c*4+0];
                    float t1 = w0*A[c*4+1] + w1*A[12+c*4+1] + w2*A[24+c*4+1] + w3*A[36+c*4+1] + w4*A[48+c*4+1];
                    float t2 = w0*A[c*4+2] + w1*A[12+c*4+2] + w2*A[24+c*4+2] + w3*A[36+c*4+2] + w4*A[48+c*4+2];
                    float t3 = w0*A[c*4+3] + w1*A[12+c*4+3] + w2*A[24+c*4+3] + w3*A[36+c*4+3] + w4*A[48+c*4+3];
                    float val = t0*p0 + t1*p1 + t2*p2 + t3 + ldf(transl, m*3 + c, f32);
                    stf(out, (m*NV + v)*3 + c, val, f32);
                }
            }
        }
        __syncthreads();
    }
}

__global__ __launch_bounds__(64) void k_lmk(const void* __restrict__ verts,
                                            const void* __restrict__ bary,
                                            const int* __restrict__ faces,
                                            const void* __restrict__ lmk_idx,
                                            const void* __restrict__ transl,
                                            const float* __restrict__ reg,
                                            const void* __restrict__ shape_p,
                                            void* __restrict__ out) {
    int f32 = probe_f32(shape_p);
    int i64 = probe_i64(lmk_idx);
    int b = blockIdx.x, tid = threadIdx.x;
    if (b == 0 && tid == 63)
        stf(out, (long)BATCH*NV*3 + (long)BATCH*NLMK*3, reg[0], f32);
    if (tid >= NLMK) return;
    int f = i64 ? (int)((const long long*)lmk_idx)[tid]
                : ((const int*)lmk_idx)[tid];
    float acc[3] = {0.f, 0.f, 0.f};
    float bsum = 0.f;
    for (int fi = 0; fi < 3; ++fi) {
        int vi = faces[f*3 + fi];
        float bc = ldf(bary, tid*3 + fi, f32);
        bsum += bc;
#pragma unroll
        for (int c = 0; c < 3; ++c)
            acc[c] += bc * ldf(verts, ((long)b*NV + vi)*3 + c, f32);
    }
#pragma unroll
    for (int c = 0; c < 3; ++c) {
        float val = acc[c] + (1.f - bsum) * ldf(transl, b*3 + c, f32);
        stf(out, (long)BATCH*NV*3 + ((long)b*NLMK + tid)*3 + c, val, f32);
    }
}

extern "C" void kernel_launch(void* const* d_in, const int* in_sizes, int n_in,
                              void* d_out, int out_size, void* d_ws, size_t ws_size,
                              hipStream_t stream) {
    const void* shape_p   = d_in[0];
    const void* expr_p    = d_in[1];
    const void* grot      = d_in[2];
    const void* neck      = d_in[3];
    const void* jaw       = d_in[4];
    const void* eye       = d_in[5];
    const void* transl    = d_in[6];
    const void* v_templ   = d_in[7];
    const void* shapedirs = d_in[8];
    const void* posedirs  = d_in[9];
    const void* Jreg      = d_in[10];
    const void* weights   = d_in[11];
    const void* bary      = d_in[12];
    const int*  faces     = (const int*)d_in[14];
    const void* lmk_idx   = d_in[15];

    char* ws = (char*)d_ws;
    float* JS      = (float*)(ws + WS_JS);
    float* baseJ   = (float*)(ws + WS_BASEJ);
    float* reg     = (float*)(ws + WS_REG);
    int*   flags   = (int*)(ws + WS_FLAGS);
    float* Amat    = (float*)(ws + WS_AMAT);
    __hip_bfloat16* Act = (__hip_bfloat16*)(ws + WS_ACT);
    __hip_bfloat16* Wb  = (__hip_bfloat16*)(ws + WS_WB);
    float* PART    = (float*)d_out;   // scratch before verts are written
    bool big = ws_size >= (size_t)WS_FULL;

    if (big) {
        k_prep<<<PK_BETA_BLKS + PK_POSE_BLKS + PK_JS_BLKS, 256, 0, stream>>>(
            shapedirs, posedirs, Jreg, v_templ, shape_p, reg, JS, baseJ, Wb, PART);
        k_js_red<<<dim3(24, 6), 256, 0, stream>>>(PART, JS, baseJ);
    } else {
        k_init<<<24, 256, 0, stream>>>((float*)ws, shape_p, lmk_idx, flags);
        k_js_atomic<<<dim3(3, 64), 256, 0, stream>>>(Jreg, shapedirs, v_templ, flags, JS, baseJ);
    }
    k_batch<<<BATCH, 64, 0, stream>>>(shape_p, expr_p, grot, neck, jaw, eye,
                                      JS, baseJ, Act, Amat, reg);
    if (big) {
        k_gemm_lbs_big<<<GGRID, 512, 0, stream>>>(Act, Wb, v_templ, Amat,
                                                  weights, transl, shape_p, d_out);
    } else {
        dim3 grid(BATCH/256, (N3 + BN - 1)/BN);
        k_gemm_lbs_small<<<grid, 256, 0, stream>>>(Act, shapedirs, posedirs, v_templ,
                                                   Amat, weights, transl, flags, d_out);
    }
    k_lmk<<<BATCH, 64, 0, stream>>>(d_out, bary, faces, lmk_idx, transl, reg, shape_p, d_out);
}